// Round 14
// baseline (176.817 us; speedup 1.0000x reference)
//
#include <hip/hip_runtime.h>
#include <math.h>

#define Bb 2
#define Nn 512
#define RR 1024
#define HH 8
#define PROJC 704
#define CONCATC 1280
#define PSTRIDE 1280
#define NSPLIT 8
#define CH 64

#define SCALAR_SCALE 0.14433756729740643f
#define POINT_SCALE  0.13608276348795434f
#define PAIR_SCALE   0.5773502691896258f

typedef __attribute__((ext_vector_type(4))) float f32x4;
typedef __attribute__((ext_vector_type(8))) short short8;
typedef __attribute__((ext_vector_type(8))) unsigned short ush8;

__device__ __forceinline__ float wred_sum(float v) {
#pragma unroll
  for (int o = 1; o < 64; o <<= 1) v += __shfl_xor(v, o);
  return v;
}
__device__ __forceinline__ float wred_max(float v) {
#pragma unroll
  for (int o = 1; o < 64; o <<= 1) v = fmaxf(v, __shfl_xor(v, o));
  return v;
}
__device__ __forceinline__ unsigned short f2bf(float f) {
  unsigned int u = __float_as_uint(f);
  unsigned int r = (u + 0x7FFFu + ((u >> 16) & 1u)) >> 16;
  return (unsigned short)r;
}

// ---------------- 1. gather + transpose + cvt Wcat_t bf16 [704][512]
__global__ __launch_bounds__(256) void gather_wcat_t(
    const float* __restrict__ Wqs, const float* __restrict__ Wks,
    const float* __restrict__ Wvs, const float* __restrict__ Wqp,
    const float* __restrict__ Wkp, const float* __restrict__ Wvp,
    unsigned short* __restrict__ Wt) {
  int c = blockIdx.x;
  for (int k = threadIdx.x; k < 512; k += 256) {
    float val = 0.f;
    if (c < 128)      val = Wqs[k * 128 + c];
    else if (c < 256) val = Wks[k * 128 + c - 128];
    else if (c < 384) val = Wvs[k * 128 + c - 256];
    else if (c < 480) val = Wqp[k * 96 + c - 384];
    else if (c < 576) val = Wkp[k * 96 + c - 480];
    else if (c < 672) val = Wvp[k * 96 + c - 576];
    Wt[(size_t)c * 512 + k] = f2bf(val);
  }
}

// ---------------- 2. transpose+cvt 4 weights: f32 [K][512] -> bf16 [512][K]
__global__ __launch_bounds__(256) void transp_cvt4(
    const float* __restrict__ w0, const float* __restrict__ w1,
    const float* __restrict__ w2, const float* __restrict__ w3,
    unsigned short* __restrict__ o0, unsigned short* __restrict__ o1,
    unsigned short* __restrict__ o2, unsigned short* __restrict__ o3) {
  int z = blockIdx.z;
  const float* in = (z == 0) ? w0 : (z == 1) ? w1 : (z == 2) ? w2 : w3;
  unsigned short* out = (z == 0) ? o0 : (z == 1) ? o1 : (z == 2) ? o2 : o3;
  int K = (z == 0) ? 1280 : 512;
  int k0 = blockIdx.y * 32, n0 = blockIdx.x * 32;
  if (k0 >= K) return;
  __shared__ float tile[32][33];
  int t = threadIdx.x;
  int r = t >> 3, cq = (t & 7) * 4;
  float4 v = *(const float4*)&in[(size_t)(k0 + r) * 512 + n0 + cq];
  tile[r][cq] = v.x; tile[r][cq + 1] = v.y; tile[r][cq + 2] = v.z; tile[r][cq + 3] = v.w;
  __syncthreads();
  ushort4 o4;
  o4.x = f2bf(tile[cq + 0][r]);
  o4.y = f2bf(tile[cq + 1][r]);
  o4.z = f2bf(tile[cq + 2][r]);
  o4.w = f2bf(tile[cq + 3][r]);
  *(ushort4*)&out[(size_t)(n0 + r) * K + k0 + cq] = o4;
}

// ---------------- 3. bf16 MFMA GEMM, 32x64 tile (full-grid coverage)
__global__ __launch_bounds__(256) void gemm_bf16_32(
    const float* __restrict__ A, int lda,
    const unsigned short* __restrict__ Bt, int K,
    float* __restrict__ C, int ldc,
    const float* __restrict__ bias, int relu) {
  __shared__ unsigned short As[32][72];
  __shared__ unsigned short Bs[64][72];
  int t = threadIdx.x;
  int lane = t & 63, w = t >> 6;
  int wc = w * 16;
  int fr = lane & 15, fk = (lane >> 4) * 8;
  f32x4 zero = {0.f, 0.f, 0.f, 0.f};
  f32x4 acc0 = zero, acc1 = zero;
  int bm = blockIdx.y * 32, bn = blockIdx.x * 64;
  int ar = t >> 3, ac = (t & 7) * 8;
  int br = t >> 2, bc = (t & 3) * 16;
  const float* Arow = A + (size_t)(bm + ar) * lda + ac;
  const unsigned short* Brow = Bt + (size_t)(bn + br) * K + bc;
  for (int k0 = 0; k0 < K; k0 += 64) {
    float4 a0 = *(const float4*)(Arow + k0);
    float4 a1 = *(const float4*)(Arow + k0 + 4);
    ush8 ap;
    ap[0] = f2bf(a0.x); ap[1] = f2bf(a0.y); ap[2] = f2bf(a0.z); ap[3] = f2bf(a0.w);
    ap[4] = f2bf(a1.x); ap[5] = f2bf(a1.y); ap[6] = f2bf(a1.z); ap[7] = f2bf(a1.w);
    ush8 b0 = *(const ush8*)(Brow + k0);
    ush8 b1 = *(const ush8*)(Brow + k0 + 8);
    *(ush8*)&As[ar][ac] = ap;
    *(ush8*)&Bs[br][bc] = b0;
    *(ush8*)&Bs[br][bc + 8] = b1;
    __syncthreads();
#pragma unroll
    for (int kk = 0; kk < 64; kk += 32) {
      short8 af0 = *(const short8*)&As[fr][kk + fk];
      short8 af1 = *(const short8*)&As[16 + fr][kk + fk];
      short8 bf = *(const short8*)&Bs[wc + fr][kk + fk];
      acc0 = __builtin_amdgcn_mfma_f32_16x16x32_bf16(af0, bf, acc0, 0, 0, 0);
      acc1 = __builtin_amdgcn_mfma_f32_16x16x32_bf16(af1, bf, acc1, 0, 0, 0);
    }
    __syncthreads();
  }
  int col = bn + wc + fr;
  float bv = bias ? bias[col] : 0.f;
#pragma unroll
  for (int mi = 0; mi < 2; mi++) {
    f32x4 av = (mi == 0) ? acc0 : acc1;
#pragma unroll
    for (int r = 0; r < 4; r++) {
      int row = bm + mi * 16 + (lane >> 4) * 4 + r;
      float v2 = av[r] + bv;
      if (relu) v2 = fmaxf(v2, 0.f);
      C[(size_t)row * ldc + col] = v2;
    }
  }
}

// ---------------- 4. rotate/translate points to global
__global__ __launch_bounds__(128) void pointxform(
    const float* __restrict__ proj, const float* __restrict__ rot,
    const float* __restrict__ trans, float* __restrict__ qp,
    float* __restrict__ kp, float* __restrict__ vp) {
  int bn = blockIdx.x;
  int t = threadIdx.x;
  __shared__ float R[9];
  __shared__ float T[3];
  if (t < 9) R[t] = rot[bn * 9 + t];
  if (t < 3) T[t] = trans[bn * 3 + t];
  __syncthreads();
  if (t < 96) {
    int which = t >> 5;
    int pt = t & 31;
    const float* src = proj + (size_t)bn * PROJC + 384 + which * 96 + pt * 3;
    float c0 = src[0], c1 = src[1], c2 = src[2];
    float* dst = (which == 0 ? qp : (which == 1 ? kp : vp)) + (size_t)bn * 96 + pt * 3;
#pragma unroll
    for (int r = 0; r < 3; r++)
      dst[r] = c0 * R[0 * 3 + r] + c1 * R[1 * 3 + r] + c2 * R[2 * 3 + r] + T[r];
  }
}

// ---------------- 5. split-j fused pass: 4 barriers (merged phases)
__global__ __launch_bounds__(256) void flash_split(
    const float* __restrict__ pair, const float* __restrict__ Wpair,
    const float* __restrict__ proj, const float* __restrict__ qp,
    const float* __restrict__ kp, const float* __restrict__ vp,
    const float* __restrict__ pw, const float* __restrict__ b_pair,
    float* __restrict__ pbuf) {
  int bi = blockIdx.x, c = blockIdx.y;
  int b = bi >> 9;
  int j0 = c * CH;
  int t = threadIdx.x;
  __shared__ unsigned short pairN[64][136];   // bf16 [j][d]
  __shared__ unsigned short WT[16][136];      // bf16 [h][d], rows 8-15 zero
  __shared__ unsigned short Pb[16][72];       // bf16 [h][j], rows 8-15 zero
  __shared__ float L[64][9];                  // scalar+point logits
  __shared__ float Lp[64][9];                 // pair logits (MFMA1 out)
  __shared__ float Pf[8][68];
  __shared__ float qs[128], qpi[96], wh[8], bp[8];
  __shared__ float msh[8], lsh[8];

  const float* pbase = pair + ((size_t)bi * 512 + j0) * 128;

  // ---- stage: pairN (coalesced+cvt), qs/qpi/wh/bp, WT, zero pads
#pragma unroll
  for (int it = 0; it < 8; it++) {
    int f = it * 256 + t;
    int j = f >> 5, dq = f & 31;
    float4 v = *(const float4*)&pbase[(size_t)j * 128 + dq * 4];
    ushort4 o;
    o.x = f2bf(v.x); o.y = f2bf(v.y); o.z = f2bf(v.z); o.w = f2bf(v.w);
    *(ushort4*)&pairN[j][dq * 4] = o;
  }
  if (t < 32) *(float4*)&qs[t * 4] = *(const float4*)&proj[(size_t)bi * PROJC + t * 4];
  if (t >= 32 && t < 56) *(float4*)&qpi[(t - 32) * 4] = *(const float4*)&qp[(size_t)bi * 96 + (t - 32) * 4];
  if (t >= 56 && t < 64) {
    wh[t - 56] = 0.5f * log1pf(__expf(pw[t - 56])) * POINT_SCALE;
    bp[t - 56] = b_pair[t - 56] * PAIR_SCALE;
  }
  if (t >= 64 && t < 192) {
    int d = t - 64;
    float4 a = *(const float4*)&Wpair[d * 8];
    float4 b2 = *(const float4*)&Wpair[d * 8 + 4];
    WT[0][d] = f2bf(a.x);  WT[1][d] = f2bf(a.y);
    WT[2][d] = f2bf(a.z);  WT[3][d] = f2bf(a.w);
    WT[4][d] = f2bf(b2.x); WT[5][d] = f2bf(b2.y);
    WT[6][d] = f2bf(b2.z); WT[7][d] = f2bf(b2.w);
  }
  {
    unsigned int* wz = (unsigned int*)&WT[8][0];
    for (int idx = t; idx < 8 * 68; idx += 256) wz[idx] = 0;
    unsigned int* pz = (unsigned int*)&Pb[8][0];
    for (int idx = t; idx < 8 * 36; idx += 256) pz[idx] = 0;
  }
  __syncthreads();

  // ==== region A: MFMA1 (matrix pipe) + phase 0 (VALU+global) — overlapped
  {
    int w = t >> 6, lane = t & 63;
    int fr = lane & 15, fko = (lane >> 4) * 8;
    f32x4 acc = {0.f, 0.f, 0.f, 0.f};
#pragma unroll
    for (int kk = 0; kk < 128; kk += 32) {
      short8 af = *(const short8*)&WT[fr][kk + fko];
      short8 bf = *(const short8*)&pairN[w * 16 + fr][kk + fko];
      acc = __builtin_amdgcn_mfma_f32_16x16x32_bf16(af, bf, acc, 0, 0, 0);
    }
    int row0 = (lane >> 4) * 4;
    if (row0 < 8) {
      int j = w * 16 + fr;
#pragma unroll
      for (int r = 0; r < 4; r++)
        Lp[j][row0 + r] = acc[r] * PAIR_SCALE;
    }
  }
  {
    const float* kbase = proj + ((size_t)b * 512 + j0) * PROJC + 128;
    const float* kpbase = kp + ((size_t)b * 512 + j0) * 96;
    int h = t & 7;
#pragma unroll
    for (int r = 0; r < 2; r++) {
      int j = r * 32 + (t >> 3);
      const float* kr = kbase + (size_t)j * PROJC + h * 16;
      const float* kpr = kpbase + (size_t)j * 96 + h * 12;
      float s = 0.f;
#pragma unroll
      for (int dd = 0; dd < 16; dd++) s += qs[h * 16 + dd] * kr[dd];
      float d2 = 0.f;
#pragma unroll
      for (int p = 0; p < 12; p++) {
        float df = qpi[h * 12 + p] - kpr[p];
        d2 += df * df;
      }
      L[j][h] = s * SCALAR_SCALE - wh[h] * d2 + bp[h];
    }
  }
  __syncthreads();

  // ==== region B: softmax (max + exp + sum fused per wave; wave w2 owns 2 heads)
  {
    int j = t & 63, w2 = t >> 6;
    int h0 = w2 * 2, h1 = h0 + 1;
    float l0 = L[j][h0] + Lp[j][h0];
    float l1 = L[j][h1] + Lp[j][h1];
    float m0 = wred_max(l0);
    float m1 = wred_max(l1);
    float p0 = __expf(l0 - m0);
    float p1 = __expf(l1 - m1);
    Pf[h0][j] = p0; Pf[h1][j] = p1;
    Pb[h0][j] = f2bf(p0); Pb[h1][j] = f2bf(p1);
    float s0 = wred_sum(p0);
    float s1 = wred_sum(p1);
    if (j == 0) {
      msh[h0] = m0; msh[h1] = m1;
      lsh[h0] = s0; lsh[h1] = s1;
    }
  }
  __syncthreads();

  float* po = pbuf + ((size_t)bi * NSPLIT + c) * PSTRIDE;

  // ==== region C: MFMA3 + phase 4 + partial writes
  {
    int lane = t & 63, w = t >> 6;
    int colm = lane & 15;
    int kgrp = (lane >> 4) * 8;
#pragma unroll
    for (int mi = 0; mi < 2; mi++) {
      int dt = w * 2 + mi;
      f32x4 acc = {0.f, 0.f, 0.f, 0.f};
#pragma unroll
      for (int kk = 0; kk < 64; kk += 32) {
        short8 af;
#pragma unroll
        for (int q = 0; q < 8; q++)
          af[q] = ((const short*)&pairN[kk + kgrp + q][0])[dt * 16 + colm];
        short8 bf = *(const short8*)&Pb[colm][kk + kgrp];
        acc = __builtin_amdgcn_mfma_f32_16x16x32_bf16(af, bf, acc, 0, 0, 0);
      }
      if (colm < 8) {
        int row0 = (lane >> 4) * 4;
#pragma unroll
        for (int r = 0; r < 4; r++)
          po[colm * 128 + dt * 16 + row0 + r] = acc[r];
      }
    }
  }
  float accs = 0.f, accg = 0.f;
  if (t < 128) {
    int hs = t >> 4;
    const float* vb = proj + ((size_t)b * 512 + j0) * PROJC + 256 + t;
#pragma unroll 16
    for (int j = 0; j < CH; j++) accs += Pf[hs][j] * vb[(size_t)j * PROJC];
    po[1024 + t] = accs;
  } else if (t < 224) {
    int ix = t - 128, hvv = ix / 12;
    const float* vb = vp + ((size_t)b * 512 + j0) * 96 + ix;
#pragma unroll 16
    for (int j = 0; j < CH; j++) accg += Pf[hvv][j] * vb[(size_t)j * 96];
    po[1152 + ix] = accg;
  }
  if (t < 8) { po[1248 + t] = msh[t]; po[1256 + t] = lsh[t]; }
}

// ---------------- 6. combine splits + frame transform + norms -> concat
__global__ __launch_bounds__(256) void combine_splits(
    const float* __restrict__ pbuf, const float* __restrict__ rot,
    const float* __restrict__ trans, float* __restrict__ concat) {
  int bi = blockIdx.x;
  int t = threadIdx.x;
  __shared__ float sc[NSPLIT][8];
  __shared__ float pg[96], plcl[96];
  __shared__ float Rm[9], Tv[3];
  if (t < 9) Rm[t] = rot[bi * 9 + t];
  if (t < 3) Tv[t] = trans[bi * 3 + t];
  const float* pb = pbuf + (size_t)bi * NSPLIT * PSTRIDE;
  if (t < 8) {
    float m[NSPLIT], lv[NSPLIT];
    float M = -1e30f;
#pragma unroll
    for (int cs = 0; cs < NSPLIT; cs++) {
      m[cs] = pb[cs * PSTRIDE + 1248 + t];
      lv[cs] = pb[cs * PSTRIDE + 1256 + t];
      M = fmaxf(M, m[cs]);
    }
    float D = 0.f, s[NSPLIT];
#pragma unroll
    for (int cs = 0; cs < NSPLIT; cs++) {
      s[cs] = __expf(m[cs] - M);
      D += lv[cs] * s[cs];
    }
    float inv = 1.f / D;
#pragma unroll
    for (int cs = 0; cs < NSPLIT; cs++) sc[cs][t] = s[cs] * inv;
  }
  __syncthreads();
  float* crow = concat + (size_t)bi * CONCATC;
#pragma unroll
  for (int q = 0; q < 4; q++) {
    int idx = q * 256 + t;
    int h = idx >> 7;
    float v = 0.f;
#pragma unroll
    for (int cs = 0; cs < NSPLIT; cs++) v += pb[cs * PSTRIDE + idx] * sc[cs][h];
    crow[256 + idx] = v;
  }
  if (t < 128) {
    int h = t >> 4;
    float v = 0.f;
#pragma unroll
    for (int cs = 0; cs < NSPLIT; cs++) v += pb[cs * PSTRIDE + 1024 + t] * sc[cs][h];
    crow[t] = v;
  } else if (t < 224) {
    int ix = t - 128, h = ix / 12;
    float v = 0.f;
#pragma unroll
    for (int cs = 0; cs < NSPLIT; cs++) v += pb[cs * PSTRIDE + 1152 + ix] * sc[cs][h];
    pg[ix] = v;
  }
  __syncthreads();
  if (t < 96) {
    int hp = t / 3, cc = t % 3;
    float v = 0.f;
#pragma unroll
    for (int r = 0; r < 3; r++) v += Rm[cc * 3 + r] * (pg[hp * 3 + r] - Tv[r]);
    plcl[t] = v;
    crow[128 + t] = v;
  }
  __syncthreads();
  if (t < 32) {
    float v0 = plcl[t * 3], v1 = plcl[t * 3 + 1], v2 = plcl[t * 3 + 2];
    crow[224 + t] = sqrtf(v0 * v0 + v1 * v1 + v2 * v2 + 1e-8f);
  }
}

// ---------------- 7. layernorm (+residual)
__global__ __launch_bounds__(256) void ln_kernel(
    const float* __restrict__ in, const float* __restrict__ res,
    const float* __restrict__ g, const float* __restrict__ bt,
    float* __restrict__ out) {
  int row = blockIdx.x;
  int t = threadIdx.x;
  __shared__ float red[8];
  size_t base = (size_t)row * 512;
  float v0 = in[base + t] + res[base + t];
  float v1 = in[base + t + 256] + res[base + t + 256];
  int wid = t >> 6, lane = t & 63;
  float s = wred_sum(v0 + v1);
  if (lane == 0) red[wid] = s;
  __syncthreads();
  float mean = (red[0] + red[1] + red[2] + red[3]) * (1.f / 512.f);
  float d0 = v0 - mean, d1 = v1 - mean;
  float q = wred_sum(d0 * d0 + d1 * d1);
  __syncthreads();
  if (lane == 0) red[wid] = q;
  __syncthreads();
  float var = (red[0] + red[1] + red[2] + red[3]) * (1.f / 512.f);
  float rs = rsqrtf(var + 1e-3f);
  out[base + t] = d0 * rs * g[t] + bt[t];
  out[base + t + 256] = d1 * rs * g[t + 256] + bt[t + 256];
}

// ---------------------------------------------------------------- launcher
extern "C" void kernel_launch(void* const* d_in, const int* in_sizes, int n_in,
                              void* d_out, int out_size, void* d_ws, size_t ws_size,
                              hipStream_t stream) {
  const float* x      = (const float*)d_in[0];
  const float* pair   = (const float*)d_in[1];
  const float* rot    = (const float*)d_in[2];
  const float* trans  = (const float*)d_in[3];
  const float* Wqs    = (const float*)d_in[4];
  const float* Wks    = (const float*)d_in[5];
  const float* Wvs    = (const float*)d_in[6];
  const float* Wqp    = (const float*)d_in[7];
  const float* Wkp    = (const float*)d_in[8];
  const float* Wvp    = (const float*)d_in[9];
  const float* pw     = (const float*)d_in[10];
  const float* Wpair  = (const float*)d_in[11];
  const float* b_pair = (const float*)d_in[12];
  const float* Wo     = (const float*)d_in[13];
  const float* bo     = (const float*)d_in[14];
  const float* ln1g   = (const float*)d_in[15];
  const float* ln1b   = (const float*)d_in[16];
  const float* ln2g   = (const float*)d_in[17];
  const float* ln2b   = (const float*)d_in[18];
  const float* ffw1   = (const float*)d_in[19];
  const float* ffb1   = (const float*)d_in[20];
  const float* ffw2   = (const float*)d_in[21];
  const float* ffb2   = (const float*)d_in[22];
  const float* ffw3   = (const float*)d_in[23];
  const float* ffb3   = (const float*)d_in[24];
  float* out = (float*)d_out;

  float* ws = (float*)d_ws;
  unsigned short* Wcat_t = (unsigned short*)ws; ws += (704 * 512) / 2;
  unsigned short* Wo_t   = (unsigned short*)ws; ws += (512 * 1280) / 2;
  unsigned short* ff1_t  = (unsigned short*)ws; ws += (512 * 512) / 2;
  unsigned short* ff2_t  = (unsigned short*)ws; ws += (512 * 512) / 2;
  unsigned short* ff3_t  = (unsigned short*)ws; ws += (512 * 512) / 2;
  float* proj   = ws; ws += (size_t)RR * PROJC;
  float* qp     = ws; ws += RR * 96;
  float* kp     = ws; ws += RR * 96;
  float* vp     = ws; ws += RR * 96;
  float* pbuf   = ws; ws += (size_t)RR * NSPLIT * PSTRIDE;
  float* concat = ws; ws += (size_t)RR * CONCATC;
  float* tmp1   = ws; ws += RR * 512;
  float* a      = ws; ws += RR * 512;
  float* h1     = ws; ws += RR * 512;
  float* h2     = ws; ws += RR * 512;
  float* f      = ws; ws += RR * 512;

  dim3 b256(256);
  hipLaunchKernelGGL(gather_wcat_t, dim3(704), b256, 0, stream,
                     Wqs, Wks, Wvs, Wqp, Wkp, Wvp, Wcat_t);
  hipLaunchKernelGGL(transp_cvt4, dim3(16, 40, 4), b256, 0, stream,
                     Wo, ffw1, ffw2, ffw3, Wo_t, ff1_t, ff2_t, ff3_t);
  hipLaunchKernelGGL(gemm_bf16_32, dim3(11, 32), b256, 0, stream,
                     x, 512, Wcat_t, 512, proj, PROJC, (const float*)nullptr, 0);
  hipLaunchKernelGGL(pointxform, dim3(RR), dim3(128), 0, stream,
                     proj, rot, trans, qp, kp, vp);
  hipLaunchKernelGGL(flash_split, dim3(RR, NSPLIT), b256, 0, stream,
                     pair, Wpair, proj, qp, kp, vp, pw, b_pair, pbuf);
  hipLaunchKernelGGL(combine_splits, dim3(RR), b256, 0, stream,
                     pbuf, rot, trans, concat);
  hipLaunchKernelGGL(gemm_bf16_32, dim3(8, 32), b256, 0, stream,
                     concat, CONCATC, Wo_t, 1280, tmp1, 512, bo, 0);
  hipLaunchKernelGGL(ln_kernel, dim3(RR), b256, 0, stream, tmp1, x, ln1g, ln1b, a);
  hipLaunchKernelGGL(gemm_bf16_32, dim3(8, 32), b256, 0, stream,
                     a, 512, ff1_t, 512, h1, 512, ffb1, 1);
  hipLaunchKernelGGL(gemm_bf16_32, dim3(8, 32), b256, 0, stream,
                     h1, 512, ff2_t, 512, h2, 512, ffb2, 1);
  hipLaunchKernelGGL(gemm_bf16_32, dim3(8, 32), b256, 0, stream,
                     h2, 512, ff3_t, 512, f, 512, ffb3, 0);
  hipLaunchKernelGGL(ln_kernel, dim3(RR), b256, 0, stream, f, a, ln2g, ln2b, out);
}

// Round 15
// 174.467 us; speedup vs baseline: 1.0135x; 1.0135x over previous
//
#include <hip/hip_runtime.h>
#include <math.h>

#define Bb 2
#define Nn 512
#define RR 1024
#define HH 8
#define PROJC 704
#define CONCATC 1280
#define PSTRIDE 1280
#define NSPLIT 8
#define CH 64

#define SCALAR_SCALE 0.14433756729740643f
#define POINT_SCALE  0.13608276348795434f
#define PAIR_SCALE   0.5773502691896258f

typedef __attribute__((ext_vector_type(4))) float f32x4;
typedef __attribute__((ext_vector_type(8))) short short8;
typedef __attribute__((ext_vector_type(8))) unsigned short ush8;

__device__ __forceinline__ float wred_sum(float v) {
#pragma unroll
  for (int o = 1; o < 64; o <<= 1) v += __shfl_xor(v, o);
  return v;
}
__device__ __forceinline__ unsigned short f2bf(float f) {
  unsigned int u = __float_as_uint(f);
  unsigned int r = (u + 0x7FFFu + ((u >> 16) & 1u)) >> 16;
  return (unsigned short)r;
}

// ---------------- 1. gather + transpose + cvt Wcat_t bf16 [704][512]
__global__ __launch_bounds__(256) void gather_wcat_t(
    const float* __restrict__ Wqs, const float* __restrict__ Wks,
    const float* __restrict__ Wvs, const float* __restrict__ Wqp,
    const float* __restrict__ Wkp, const float* __restrict__ Wvp,
    unsigned short* __restrict__ Wt) {
  int c = blockIdx.x;
  for (int k = threadIdx.x; k < 512; k += 256) {
    float val = 0.f;
    if (c < 128)      val = Wqs[k * 128 + c];
    else if (c < 256) val = Wks[k * 128 + c - 128];
    else if (c < 384) val = Wvs[k * 128 + c - 256];
    else if (c < 480) val = Wqp[k * 96 + c - 384];
    else if (c < 576) val = Wkp[k * 96 + c - 480];
    else if (c < 672) val = Wvp[k * 96 + c - 576];
    Wt[(size_t)c * 512 + k] = f2bf(val);
  }
}

// ---------------- 2. transpose+cvt 4 weights: f32 [K][512] -> bf16 [512][K]
__global__ __launch_bounds__(256) void transp_cvt4(
    const float* __restrict__ w0, const float* __restrict__ w1,
    const float* __restrict__ w2, const float* __restrict__ w3,
    unsigned short* __restrict__ o0, unsigned short* __restrict__ o1,
    unsigned short* __restrict__ o2, unsigned short* __restrict__ o3) {
  int z = blockIdx.z;
  const float* in = (z == 0) ? w0 : (z == 1) ? w1 : (z == 2) ? w2 : w3;
  unsigned short* out = (z == 0) ? o0 : (z == 1) ? o1 : (z == 2) ? o2 : o3;
  int K = (z == 0) ? 1280 : 512;
  int k0 = blockIdx.y * 32, n0 = blockIdx.x * 32;
  if (k0 >= K) return;
  __shared__ float tile[32][33];
  int t = threadIdx.x;
  int r = t >> 3, cq = (t & 7) * 4;
  float4 v = *(const float4*)&in[(size_t)(k0 + r) * 512 + n0 + cq];
  tile[r][cq] = v.x; tile[r][cq + 1] = v.y; tile[r][cq + 2] = v.z; tile[r][cq + 3] = v.w;
  __syncthreads();
  ushort4 o4;
  o4.x = f2bf(tile[cq + 0][r]);
  o4.y = f2bf(tile[cq + 1][r]);
  o4.z = f2bf(tile[cq + 2][r]);
  o4.w = f2bf(tile[cq + 3][r]);
  *(ushort4*)&out[(size_t)(n0 + r) * K + k0 + cq] = o4;
}

// ---------------- 3. bf16 MFMA GEMM, 32x64 tile (full-grid coverage)
__global__ __launch_bounds__(256) void gemm_bf16_32(
    const float* __restrict__ A, int lda,
    const unsigned short* __restrict__ Bt, int K,
    float* __restrict__ C, int ldc,
    const float* __restrict__ bias, int relu) {
  __shared__ unsigned short As[32][72];
  __shared__ unsigned short Bs[64][72];
  int t = threadIdx.x;
  int lane = t & 63, w = t >> 6;
  int wc = w * 16;
  int fr = lane & 15, fk = (lane >> 4) * 8;
  f32x4 zero = {0.f, 0.f, 0.f, 0.f};
  f32x4 acc0 = zero, acc1 = zero;
  int bm = blockIdx.y * 32, bn = blockIdx.x * 64;
  int ar = t >> 3, ac = (t & 7) * 8;
  int br = t >> 2, bc = (t & 3) * 16;
  const float* Arow = A + (size_t)(bm + ar) * lda + ac;
  const unsigned short* Brow = Bt + (size_t)(bn + br) * K + bc;
  for (int k0 = 0; k0 < K; k0 += 64) {
    float4 a0 = *(const float4*)(Arow + k0);
    float4 a1 = *(const float4*)(Arow + k0 + 4);
    ush8 ap;
    ap[0] = f2bf(a0.x); ap[1] = f2bf(a0.y); ap[2] = f2bf(a0.z); ap[3] = f2bf(a0.w);
    ap[4] = f2bf(a1.x); ap[5] = f2bf(a1.y); ap[6] = f2bf(a1.z); ap[7] = f2bf(a1.w);
    ush8 b0 = *(const ush8*)(Brow + k0);
    ush8 b1 = *(const ush8*)(Brow + k0 + 8);
    *(ush8*)&As[ar][ac] = ap;
    *(ush8*)&Bs[br][bc] = b0;
    *(ush8*)&Bs[br][bc + 8] = b1;
    __syncthreads();
#pragma unroll
    for (int kk = 0; kk < 64; kk += 32) {
      short8 af0 = *(const short8*)&As[fr][kk + fk];
      short8 af1 = *(const short8*)&As[16 + fr][kk + fk];
      short8 bf = *(const short8*)&Bs[wc + fr][kk + fk];
      acc0 = __builtin_amdgcn_mfma_f32_16x16x32_bf16(af0, bf, acc0, 0, 0, 0);
      acc1 = __builtin_amdgcn_mfma_f32_16x16x32_bf16(af1, bf, acc1, 0, 0, 0);
    }
    __syncthreads();
  }
  int col = bn + wc + fr;
  float bv = bias ? bias[col] : 0.f;
#pragma unroll
  for (int mi = 0; mi < 2; mi++) {
    f32x4 av = (mi == 0) ? acc0 : acc1;
#pragma unroll
    for (int r = 0; r < 4; r++) {
      int row = bm + mi * 16 + (lane >> 4) * 4 + r;
      float v2 = av[r] + bv;
      if (relu) v2 = fmaxf(v2, 0.f);
      C[(size_t)row * ldc + col] = v2;
    }
  }
}

// ---------------- 4. rotate/translate points to global
__global__ __launch_bounds__(128) void pointxform(
    const float* __restrict__ proj, const float* __restrict__ rot,
    const float* __restrict__ trans, float* __restrict__ qp,
    float* __restrict__ kp, float* __restrict__ vp) {
  int bn = blockIdx.x;
  int t = threadIdx.x;
  __shared__ float R[9];
  __shared__ float T[3];
  if (t < 9) R[t] = rot[bn * 9 + t];
  if (t < 3) T[t] = trans[bn * 3 + t];
  __syncthreads();
  if (t < 96) {
    int which = t >> 5;
    int pt = t & 31;
    const float* src = proj + (size_t)bn * PROJC + 384 + which * 96 + pt * 3;
    float c0 = src[0], c1 = src[1], c2 = src[2];
    float* dst = (which == 0 ? qp : (which == 1 ? kp : vp)) + (size_t)bn * 96 + pt * 3;
#pragma unroll
    for (int r = 0; r < 3; r++)
      dst[r] = c0 * R[0 * 3 + r] + c1 * R[1 * 3 + r] + c2 * R[2 * 3 + r] + T[r];
  }
}

// ---------------- 5. split-j fused pass: R13 phase order, 8-row WT/Pb
// ("garbage rows" trick), VsN-reuse MFMA for out_s, split out_pg.
__global__ __launch_bounds__(256) void flash_split(
    const float* __restrict__ pair, const float* __restrict__ Wpair,
    const float* __restrict__ proj, const float* __restrict__ qp,
    const float* __restrict__ kp, const float* __restrict__ vp,
    const float* __restrict__ pw, const float* __restrict__ b_pair,
    float* __restrict__ pbuf) {
  int bi = blockIdx.x, c = blockIdx.y;
  int b = bi >> 9;
  int j0 = c * CH;
  int t = threadIdx.x;
  __shared__ unsigned short pairN[64][136];   // bf16 [j][d]; later reused as VsN [j][dv]
  __shared__ unsigned short WT[8][136];       // bf16 [h][d]
  __shared__ unsigned short Pb[8][72];        // bf16 [h][j]
  __shared__ float L[64][9];
  __shared__ float Pf[8][68];
  __shared__ float qs[128], qpi[96], wh[8], bp[8];
  __shared__ float msh[8], lsh[8];
  __shared__ float pgpart[96];

  const float* pbase = pair + ((size_t)bi * 512 + j0) * 128;

  // ---- stage: pairN (coalesced+cvt), qs/qpi/wh/bp, WT
#pragma unroll
  for (int it = 0; it < 8; it++) {
    int f = it * 256 + t;
    int j = f >> 5, dq = f & 31;
    float4 v = *(const float4*)&pbase[(size_t)j * 128 + dq * 4];
    ushort4 o;
    o.x = f2bf(v.x); o.y = f2bf(v.y); o.z = f2bf(v.z); o.w = f2bf(v.w);
    *(ushort4*)&pairN[j][dq * 4] = o;
  }
  if (t < 32) *(float4*)&qs[t * 4] = *(const float4*)&proj[(size_t)bi * PROJC + t * 4];
  if (t >= 32 && t < 56) *(float4*)&qpi[(t - 32) * 4] = *(const float4*)&qp[(size_t)bi * 96 + (t - 32) * 4];
  if (t >= 56 && t < 64) {
    wh[t - 56] = 0.5f * log1pf(__expf(pw[t - 56])) * POINT_SCALE;
    bp[t - 56] = b_pair[t - 56] * PAIR_SCALE;
  }
  if (t >= 64 && t < 192) {
    int d = t - 64;
    float4 a = *(const float4*)&Wpair[d * 8];
    float4 b2 = *(const float4*)&Wpair[d * 8 + 4];
    WT[0][d] = f2bf(a.x);  WT[1][d] = f2bf(a.y);
    WT[2][d] = f2bf(a.z);  WT[3][d] = f2bf(a.w);
    WT[4][d] = f2bf(b2.x); WT[5][d] = f2bf(b2.y);
    WT[6][d] = f2bf(b2.z); WT[7][d] = f2bf(b2.w);
  }
  __syncthreads();

  // ---- phase 0: scalar + point logits -> L[j][h]
  {
    const float* kbase = proj + ((size_t)b * 512 + j0) * PROJC + 128;
    const float* kpbase = kp + ((size_t)b * 512 + j0) * 96;
    int h = t & 7;
#pragma unroll
    for (int r = 0; r < 2; r++) {
      int j = r * 32 + (t >> 3);
      const float* kr = kbase + (size_t)j * PROJC + h * 16;
      const float* kpr = kpbase + (size_t)j * 96 + h * 12;
      float s = 0.f;
#pragma unroll
      for (int dd = 0; dd < 16; dd++) s += qs[h * 16 + dd] * kr[dd];
      float d2 = 0.f;
#pragma unroll
      for (int p = 0; p < 12; p++) {
        float df = qpi[h * 12 + p] - kpr[p];
        d2 += df * df;
      }
      L[j][h] = s * SCALAR_SCALE - wh[h] * d2 + bp[h];
    }
  }
  __syncthreads();

  // ---- MFMA1: L[j][h] += PAIR_SCALE * (W^T x pair^T)[h][j]
  // A rows 8-15 read garbage (WT[fr&7]); they only affect C rows 8-15 (unwritten).
  {
    int w = t >> 6, lane = t & 63;
    int fr = lane & 15, fko = (lane >> 4) * 8;
    f32x4 acc = {0.f, 0.f, 0.f, 0.f};
#pragma unroll
    for (int kk = 0; kk < 128; kk += 32) {
      short8 af = *(const short8*)&WT[fr & 7][kk + fko];
      short8 bf = *(const short8*)&pairN[w * 16 + fr][kk + fko];
      acc = __builtin_amdgcn_mfma_f32_16x16x32_bf16(af, bf, acc, 0, 0, 0);
    }
    int row0 = (lane >> 4) * 4;
    if (row0 < 8) {
      int j = w * 16 + fr;
#pragma unroll
      for (int r = 0; r < 4; r++)
        L[j][row0 + r] += acc[r] * PAIR_SCALE;
    }
  }
  __syncthreads();

  // ---- local max per head
  if (t < 64) {
    int h = t >> 3, seg = t & 7;
    float m = -1e30f;
#pragma unroll
    for (int k = 0; k < 8; k++) m = fmaxf(m, L[seg * 8 + k][h]);
    m = fmaxf(m, __shfl_xor(m, 1));
    m = fmaxf(m, __shfl_xor(m, 2));
    m = fmaxf(m, __shfl_xor(m, 4));
    if (seg == 0) msh[h] = m;
  }
  __syncthreads();

  // ---- P = exp(L - m) (f32 + bf16), l per head
  {
    int j = t & 63, w2 = t >> 6;
    int h0 = w2 * 2, h1 = h0 + 1;
    float p0 = __expf(L[j][h0] - msh[h0]);
    float p1 = __expf(L[j][h1] - msh[h1]);
    Pf[h0][j] = p0; Pf[h1][j] = p1;
    Pb[h0][j] = f2bf(p0); Pb[h1][j] = f2bf(p1);
    float s0 = wred_sum(p0);
    float s1 = wred_sum(p1);
    if (j == 0) { lsh[h0] = s0; lsh[h1] = s1; }
  }
  __syncthreads();

  float* po = pbuf + ((size_t)bi * NSPLIT + c) * PSTRIDE;

  // ---- region C: MFMA3 (out_pair) + out_pg half-sums (192 threads)
  {
    int lane = t & 63, w = t >> 6;
    int colm = lane & 15;
    int kgrp = (lane >> 4) * 8;
#pragma unroll
    for (int mi = 0; mi < 2; mi++) {
      int dt = w * 2 + mi;
      f32x4 acc = {0.f, 0.f, 0.f, 0.f};
#pragma unroll
      for (int kk = 0; kk < 64; kk += 32) {
        short8 af;
#pragma unroll
        for (int q = 0; q < 8; q++)
          af[q] = ((const short*)&pairN[kk + kgrp + q][0])[dt * 16 + colm];
        short8 bf = *(const short8*)&Pb[colm & 7][kk + kgrp];
        acc = __builtin_amdgcn_mfma_f32_16x16x32_bf16(af, bf, acc, 0, 0, 0);
      }
      if (colm < 8) {
        int row0 = (lane >> 4) * 4;
#pragma unroll
        for (int r = 0; r < 4; r++)
          po[colm * 128 + dt * 16 + row0 + r] = acc[r];
      }
    }
  }
  float accg = 0.f;
  int ixg = (t < 96) ? t : t - 96;
  if (t < 192) {
    int jh = (t < 96) ? 0 : 1;
    int hvv = ixg / 12;
    const float* vb = vp + ((size_t)b * 512 + j0 + jh * 32) * 96 + ixg;
#pragma unroll 8
    for (int j = 0; j < 32; j++) accg += Pf[hvv][jh * 32 + j] * vb[(size_t)j * 96];
    if (t < 96) pgpart[ixg] = accg;
  }
  __syncthreads();   // pairN now dead; pgpart ready

  // ---- stage VsN (proj cols 256..384) into pairN
  {
    const float* vsb = proj + ((size_t)b * 512 + j0) * PROJC + 256;
#pragma unroll
    for (int it = 0; it < 8; it++) {
      int f = it * 256 + t;
      int j = f >> 5, dq = f & 31;
      float4 v = *(const float4*)&vsb[(size_t)j * PROJC + dq * 4];
      ushort4 o;
      o.x = f2bf(v.x); o.y = f2bf(v.y); o.z = f2bf(v.z); o.w = f2bf(v.w);
      *(ushort4*)&pairN[j][dq * 4] = o;
    }
  }
  if (t >= 96 && t < 192) po[1152 + ixg] = pgpart[ixg] + accg;
  if (t < 8) { po[1248 + t] = msh[t]; po[1256 + t] = lsh[t]; }
  __syncthreads();

  // ---- MFMA4: out_s. Full (8h x 128dv) product; keep block-diagonal h==dt.
  {
    int lane = t & 63, w = t >> 6;
    int colm = lane & 15;
    int kgrp = (lane >> 4) * 8;
#pragma unroll
    for (int mi = 0; mi < 2; mi++) {
      int dt = w * 2 + mi;
      f32x4 acc = {0.f, 0.f, 0.f, 0.f};
#pragma unroll
      for (int kk = 0; kk < 64; kk += 32) {
        short8 af;
#pragma unroll
        for (int q = 0; q < 8; q++)
          af[q] = ((const short*)&pairN[kk + kgrp + q][0])[dt * 16 + colm];
        short8 bf = *(const short8*)&Pb[colm & 7][kk + kgrp];
        acc = __builtin_amdgcn_mfma_f32_16x16x32_bf16(af, bf, acc, 0, 0, 0);
      }
      if (colm == dt) {
        int row0 = (lane >> 4) * 4;
#pragma unroll
        for (int r = 0; r < 4; r++)
          po[1024 + dt * 16 + row0 + r] = acc[r];
      }
    }
  }
}

// ---------------- 6. combine splits + frame transform + norms -> concat
__global__ __launch_bounds__(256) void combine_splits(
    const float* __restrict__ pbuf, const float* __restrict__ rot,
    const float* __restrict__ trans, float* __restrict__ concat) {
  int bi = blockIdx.x;
  int t = threadIdx.x;
  __shared__ float sc[NSPLIT][8];
  __shared__ float pg[96], plcl[96];
  __shared__ float Rm[9], Tv[3];
  if (t < 9) Rm[t] = rot[bi * 9 + t];
  if (t < 3) Tv[t] = trans[bi * 3 + t];
  const float* pb = pbuf + (size_t)bi * NSPLIT * PSTRIDE;
  if (t < 8) {
    float m[NSPLIT], lv[NSPLIT];
    float M = -1e30f;
#pragma unroll
    for (int cs = 0; cs < NSPLIT; cs++) {
      m[cs] = pb[cs * PSTRIDE + 1248 + t];
      lv[cs] = pb[cs * PSTRIDE + 1256 + t];
      M = fmaxf(M, m[cs]);
    }
    float D = 0.f, s[NSPLIT];
#pragma unroll
    for (int cs = 0; cs < NSPLIT; cs++) {
      s[cs] = __expf(m[cs] - M);
      D += lv[cs] * s[cs];
    }
    float inv = 1.f / D;
#pragma unroll
    for (int cs = 0; cs < NSPLIT; cs++) sc[cs][t] = s[cs] * inv;
  }
  __syncthreads();
  float* crow = concat + (size_t)bi * CONCATC;
#pragma unroll
  for (int q = 0; q < 4; q++) {
    int idx = q * 256 + t;
    int h = idx >> 7;
    float v = 0.f;
#pragma unroll
    for (int cs = 0; cs < NSPLIT; cs++) v += pb[cs * PSTRIDE + idx] * sc[cs][h];
    crow[256 + idx] = v;
  }
  if (t < 128) {
    int h = t >> 4;
    float v = 0.f;
#pragma unroll
    for (int cs = 0; cs < NSPLIT; cs++) v += pb[cs * PSTRIDE + 1024 + t] * sc[cs][h];
    crow[t] = v;
  } else if (t < 224) {
    int ix = t - 128, h = ix / 12;
    float v = 0.f;
#pragma unroll
    for (int cs = 0; cs < NSPLIT; cs++) v += pb[cs * PSTRIDE + 1152 + ix] * sc[cs][h];
    pg[ix] = v;
  }
  __syncthreads();
  if (t < 96) {
    int hp = t / 3, cc = t % 3;
    float v = 0.f;
#pragma unroll
    for (int r = 0; r < 3; r++) v += Rm[cc * 3 + r] * (pg[hp * 3 + r] - Tv[r]);
    plcl[t] = v;
    crow[128 + t] = v;
  }
  __syncthreads();
  if (t < 32) {
    float v0 = plcl[t * 3], v1 = plcl[t * 3 + 1], v2 = plcl[t * 3 + 2];
    crow[224 + t] = sqrtf(v0 * v0 + v1 * v1 + v2 * v2 + 1e-8f);
  }
}

// ---------------- 7. layernorm (+residual)
__global__ __launch_bounds__(256) void ln_kernel(
    const float* __restrict__ in, const float* __restrict__ res,
    const float* __restrict__ g, const float* __restrict__ bt,
    float* __restrict__ out) {
  int row = blockIdx.x;
  int t = threadIdx.x;
  __shared__ float red[8];
  size_t base = (size_t)row * 512;
  float v0 = in[base + t] + res[base + t];
  float v1 = in[base + t + 256] + res[base + t + 256];
  int wid = t >> 6, lane = t & 63;
  float s = wred_sum(v0 + v1);
  if (lane == 0) red[wid] = s;
  __syncthreads();
  float mean = (red[0] + red[1] + red[2] + red[3]) * (1.f / 512.f);
  float d0 = v0 - mean, d1 = v1 - mean;
  float q = wred_sum(d0 * d0 + d1 * d1);
  __syncthreads();
  if (lane == 0) red[wid] = q;
  __syncthreads();
  float var = (red[0] + red[1] + red[2] + red[3]) * (1.f / 512.f);
  float rs = rsqrtf(var + 1e-3f);
  out[base + t] = d0 * rs * g[t] + bt[t];
  out[base + t + 256] = d1 * rs * g[t + 256] + bt[t + 256];
}

// ---------------------------------------------------------------- launcher
extern "C" void kernel_launch(void* const* d_in, const int* in_sizes, int n_in,
                              void* d_out, int out_size, void* d_ws, size_t ws_size,
                              hipStream_t stream) {
  const float* x      = (const float*)d_in[0];
  const float* pair   = (const float*)d_in[1];
  const float* rot    = (const float*)d_in[2];
  const float* trans  = (const float*)d_in[3];
  const float* Wqs    = (const float*)d_in[4];
  const float* Wks    = (const float*)d_in[5];
  const float* Wvs    = (const float*)d_in[6];
  const float* Wqp    = (const float*)d_in[7];
  const float* Wkp    = (const float*)d_in[8];
  const float* Wvp    = (const float*)d_in[9];
  const float* pw     = (const float*)d_in[10];
  const float* Wpair  = (const float*)d_in[11];
  const float* b_pair = (const float*)d_in[12];
  const float* Wo     = (const float*)d_in[13];
  const float* bo     = (const float*)d_in[14];
  const float* ln1g   = (const float*)d_in[15];
  const float* ln1b   = (const float*)d_in[16];
  const float* ln2g   = (const float*)d_in[17];
  const float* ln2b   = (const float*)d_in[18];
  const float* ffw1   = (const float*)d_in[19];
  const float* ffb1   = (const float*)d_in[20];
  const float* ffw2   = (const float*)d_in[21];
  const float* ffb2   = (const float*)d_in[22];
  const float* ffw3   = (const float*)d_in[23];
  const float* ffb3   = (const float*)d_in[24];
  float* out = (float*)d_out;

  float* ws = (float*)d_ws;
  unsigned short* Wcat_t = (unsigned short*)ws; ws += (704 * 512) / 2;
  unsigned short* Wo_t   = (unsigned short*)ws; ws += (512 * 1280) / 2;
  unsigned short* ff1_t  = (unsigned short*)ws; ws += (512 * 512) / 2;
  unsigned short* ff2_t  = (unsigned short*)ws; ws += (512 * 512) / 2;
  unsigned short* ff3_t  = (unsigned short*)ws; ws += (512 * 512) / 2;
  float* proj   = ws; ws += (size_t)RR * PROJC;
  float* qp     = ws; ws += RR * 96;
  float* kp     = ws; ws += RR * 96;
  float* vp     = ws; ws += RR * 96;
  float* pbuf   = ws; ws += (size_t)RR * NSPLIT * PSTRIDE;
  float* concat = ws; ws += (size_t)RR * CONCATC;
  float* tmp1   = ws; ws += RR * 512;
  float* a      = ws; ws += RR * 512;
  float* h1     = ws; ws += RR * 512;
  float* h2     = ws; ws += RR * 512;
  float* f      = ws; ws += RR * 512;

  dim3 b256(256);
  hipLaunchKernelGGL(gather_wcat_t, dim3(704), b256, 0, stream,
                     Wqs, Wks, Wvs, Wqp, Wkp, Wvp, Wcat_t);
  hipLaunchKernelGGL(transp_cvt4, dim3(16, 40, 4), b256, 0, stream,
                     Wo, ffw1, ffw2, ffw3, Wo_t, ff1_t, ff2_t, ff3_t);
  hipLaunchKernelGGL(gemm_bf16_32, dim3(11, 32), b256, 0, stream,
                     x, 512, Wcat_t, 512, proj, PROJC, (const float*)nullptr, 0);
  hipLaunchKernelGGL(pointxform, dim3(RR), dim3(128), 0, stream,
                     proj, rot, trans, qp, kp, vp);
  hipLaunchKernelGGL(flash_split, dim3(RR, NSPLIT), b256, 0, stream,
                     pair, Wpair, proj, qp, kp, vp, pw, b_pair, pbuf);
  hipLaunchKernelGGL(combine_splits, dim3(RR), b256, 0, stream,
                     pbuf, rot, trans, concat);
  hipLaunchKernelGGL(gemm_bf16_32, dim3(8, 32), b256, 0, stream,
                     concat, CONCATC, Wo_t, 1280, tmp1, 512, bo, 0);
  hipLaunchKernelGGL(ln_kernel, dim3(RR), b256, 0, stream, tmp1, x, ln1g, ln1b, a);
  hipLaunchKernelGGL(gemm_bf16_32, dim3(8, 32), b256, 0, stream,
                     a, 512, ff1_t, 512, h1, 512, ffb1, 1);
  hipLaunchKernelGGL(gemm_bf16_32, dim3(8, 32), b256, 0, stream,
                     h1, 512, ff2_t, 512, h2, 512, ffb2, 1);
  hipLaunchKernelGGL(gemm_bf16_32, dim3(8, 32), b256, 0, stream,
                     h2, 512, ff3_t, 512, f, 512, ffb3, 0);
  hipLaunchKernelGGL(ln_kernel, dim3(RR), b256, 0, stream, f, a, ln2g, ln2b, out);
}

// Round 16
// 169.978 us; speedup vs baseline: 1.0402x; 1.0264x over previous
//
#include <hip/hip_runtime.h>
#include <math.h>

#define Bb 2
#define Nn 512
#define RR 1024
#define HH 8
#define PROJC 704
#define CONCATC 1280
#define PSTRIDE16 1280   // ushort stride per (bi,split) partial record
#define NSPLIT 8
#define CH 64

#define SCALAR_SCALE 0.14433756729740643f
#define POINT_SCALE  0.13608276348795434f
#define PAIR_SCALE   0.5773502691896258f

typedef __attribute__((ext_vector_type(4))) float f32x4;
typedef __attribute__((ext_vector_type(8))) short short8;
typedef __attribute__((ext_vector_type(8))) unsigned short ush8;

__device__ __forceinline__ float wred_sum(float v) {
#pragma unroll
  for (int o = 1; o < 64; o <<= 1) v += __shfl_xor(v, o);
  return v;
}
__device__ __forceinline__ unsigned short f2bf(float f) {
  unsigned int u = __float_as_uint(f);
  unsigned int r = (u + 0x7FFFu + ((u >> 16) & 1u)) >> 16;
  return (unsigned short)r;
}
__device__ __forceinline__ float bf2f(unsigned short u) {
  return __uint_as_float(((unsigned int)u) << 16);
}

// ---------------- 1. prep: z<4 -> transpose+cvt weights; z==4 -> gather Wcat_t
__global__ __launch_bounds__(256) void prep_weights(
    const float* __restrict__ w0, const float* __restrict__ w1,
    const float* __restrict__ w2, const float* __restrict__ w3,
    unsigned short* __restrict__ o0, unsigned short* __restrict__ o1,
    unsigned short* __restrict__ o2, unsigned short* __restrict__ o3,
    const float* __restrict__ Wqs, const float* __restrict__ Wks,
    const float* __restrict__ Wvs, const float* __restrict__ Wqp,
    const float* __restrict__ Wkp, const float* __restrict__ Wvp,
    unsigned short* __restrict__ Wt) {
  int z = blockIdx.z;
  int t = threadIdx.x;
  if (z < 4) {
    const float* in = (z == 0) ? w0 : (z == 1) ? w1 : (z == 2) ? w2 : w3;
    unsigned short* out = (z == 0) ? o0 : (z == 1) ? o1 : (z == 2) ? o2 : o3;
    int K = (z == 0) ? 1280 : 512;
    int k0 = blockIdx.y * 32, n0 = blockIdx.x * 32;
    if (k0 >= K) return;
    __shared__ float tile[32][33];
    int r = t >> 3, cq = (t & 7) * 4;
    float4 v = *(const float4*)&in[(size_t)(k0 + r) * 512 + n0 + cq];
    tile[r][cq] = v.x; tile[r][cq + 1] = v.y; tile[r][cq + 2] = v.z; tile[r][cq + 3] = v.w;
    __syncthreads();
    ushort4 o4;
    o4.x = f2bf(tile[cq + 0][r]);
    o4.y = f2bf(tile[cq + 1][r]);
    o4.z = f2bf(tile[cq + 2][r]);
    o4.w = f2bf(tile[cq + 3][r]);
    *(ushort4*)&out[(size_t)(n0 + r) * K + k0 + cq] = o4;
  } else {
    // gather Wcat_t bf16 [704][512]; grid-stride over columns
    for (int c = blockIdx.y * 16 + blockIdx.x; c < 704; c += 640) {
      for (int k = t; k < 512; k += 256) {
        float val = 0.f;
        if (c < 128)      val = Wqs[k * 128 + c];
        else if (c < 256) val = Wks[k * 128 + c - 128];
        else if (c < 384) val = Wvs[k * 128 + c - 256];
        else if (c < 480) val = Wqp[k * 96 + c - 384];
        else if (c < 576) val = Wkp[k * 96 + c - 480];
        else if (c < 672) val = Wvp[k * 96 + c - 576];
        Wt[(size_t)c * 512 + k] = f2bf(val);
      }
    }
  }
}

// ---------------- 3. bf16 MFMA GEMM, 32x64 tile (full-grid coverage)
__global__ __launch_bounds__(256) void gemm_bf16_32(
    const float* __restrict__ A, int lda,
    const unsigned short* __restrict__ Bt, int K,
    float* __restrict__ C, int ldc,
    const float* __restrict__ bias, int relu) {
  __shared__ unsigned short As[32][72];
  __shared__ unsigned short Bs[64][72];
  int t = threadIdx.x;
  int lane = t & 63, w = t >> 6;
  int wc = w * 16;
  int fr = lane & 15, fk = (lane >> 4) * 8;
  f32x4 zero = {0.f, 0.f, 0.f, 0.f};
  f32x4 acc0 = zero, acc1 = zero;
  int bm = blockIdx.y * 32, bn = blockIdx.x * 64;
  int ar = t >> 3, ac = (t & 7) * 8;
  int br = t >> 2, bc = (t & 3) * 16;
  const float* Arow = A + (size_t)(bm + ar) * lda + ac;
  const unsigned short* Brow = Bt + (size_t)(bn + br) * K + bc;
  for (int k0 = 0; k0 < K; k0 += 64) {
    float4 a0 = *(const float4*)(Arow + k0);
    float4 a1 = *(const float4*)(Arow + k0 + 4);
    ush8 ap;
    ap[0] = f2bf(a0.x); ap[1] = f2bf(a0.y); ap[2] = f2bf(a0.z); ap[3] = f2bf(a0.w);
    ap[4] = f2bf(a1.x); ap[5] = f2bf(a1.y); ap[6] = f2bf(a1.z); ap[7] = f2bf(a1.w);
    ush8 b0 = *(const ush8*)(Brow + k0);
    ush8 b1 = *(const ush8*)(Brow + k0 + 8);
    *(ush8*)&As[ar][ac] = ap;
    *(ush8*)&Bs[br][bc] = b0;
    *(ush8*)&Bs[br][bc + 8] = b1;
    __syncthreads();
#pragma unroll
    for (int kk = 0; kk < 64; kk += 32) {
      short8 af0 = *(const short8*)&As[fr][kk + fk];
      short8 af1 = *(const short8*)&As[16 + fr][kk + fk];
      short8 bf = *(const short8*)&Bs[wc + fr][kk + fk];
      acc0 = __builtin_amdgcn_mfma_f32_16x16x32_bf16(af0, bf, acc0, 0, 0, 0);
      acc1 = __builtin_amdgcn_mfma_f32_16x16x32_bf16(af1, bf, acc1, 0, 0, 0);
    }
    __syncthreads();
  }
  int col = bn + wc + fr;
  float bv = bias ? bias[col] : 0.f;
#pragma unroll
  for (int mi = 0; mi < 2; mi++) {
    f32x4 av = (mi == 0) ? acc0 : acc1;
#pragma unroll
    for (int r = 0; r < 4; r++) {
      int row = bm + mi * 16 + (lane >> 4) * 4 + r;
      float v2 = av[r] + bv;
      if (relu) v2 = fmaxf(v2, 0.f);
      C[(size_t)row * ldc + col] = v2;
    }
  }
}

// ---------------- 4. rotate/translate points to global
__global__ __launch_bounds__(128) void pointxform(
    const float* __restrict__ proj, const float* __restrict__ rot,
    const float* __restrict__ trans, float* __restrict__ qp,
    float* __restrict__ kp, float* __restrict__ vp) {
  int bn = blockIdx.x;
  int t = threadIdx.x;
  __shared__ float R[9];
  __shared__ float T[3];
  if (t < 9) R[t] = rot[bn * 9 + t];
  if (t < 3) T[t] = trans[bn * 3 + t];
  __syncthreads();
  if (t < 96) {
    int which = t >> 5;
    int pt = t & 31;
    const float* src = proj + (size_t)bn * PROJC + 384 + which * 96 + pt * 3;
    float c0 = src[0], c1 = src[1], c2 = src[2];
    float* dst = (which == 0 ? qp : (which == 1 ? kp : vp)) + (size_t)bn * 96 + pt * 3;
#pragma unroll
    for (int r = 0; r < 3; r++)
      dst[r] = c0 * R[0 * 3 + r] + c1 * R[1 * 3 + r] + c2 * R[2 * 3 + r] + T[r];
  }
}

// ---------------- 5. split-j fused pass (R15 structure; bf16 partials out)
__global__ __launch_bounds__(256) void flash_split(
    const float* __restrict__ pair, const float* __restrict__ Wpair,
    const float* __restrict__ proj, const float* __restrict__ qp,
    const float* __restrict__ kp, const float* __restrict__ vp,
    const float* __restrict__ pw, const float* __restrict__ b_pair,
    unsigned short* __restrict__ pbuf16, float* __restrict__ pml) {
  int bi = blockIdx.x, c = blockIdx.y;
  int b = bi >> 9;
  int j0 = c * CH;
  int t = threadIdx.x;
  __shared__ unsigned short pairN[64][136];
  __shared__ unsigned short WT[8][136];
  __shared__ unsigned short Pb[8][72];
  __shared__ float L[64][9];
  __shared__ float Pf[8][68];
  __shared__ float qs[128], qpi[96], wh[8], bp[8];
  __shared__ float msh[8], lsh[8];
  __shared__ float pgpart[96];

  const float* pbase = pair + ((size_t)bi * 512 + j0) * 128;

#pragma unroll
  for (int it = 0; it < 8; it++) {
    int f = it * 256 + t;
    int j = f >> 5, dq = f & 31;
    float4 v = *(const float4*)&pbase[(size_t)j * 128 + dq * 4];
    ushort4 o;
    o.x = f2bf(v.x); o.y = f2bf(v.y); o.z = f2bf(v.z); o.w = f2bf(v.w);
    *(ushort4*)&pairN[j][dq * 4] = o;
  }
  if (t < 32) *(float4*)&qs[t * 4] = *(const float4*)&proj[(size_t)bi * PROJC + t * 4];
  if (t >= 32 && t < 56) *(float4*)&qpi[(t - 32) * 4] = *(const float4*)&qp[(size_t)bi * 96 + (t - 32) * 4];
  if (t >= 56 && t < 64) {
    wh[t - 56] = 0.5f * log1pf(__expf(pw[t - 56])) * POINT_SCALE;
    bp[t - 56] = b_pair[t - 56] * PAIR_SCALE;
  }
  if (t >= 64 && t < 192) {
    int d = t - 64;
    float4 a = *(const float4*)&Wpair[d * 8];
    float4 b2 = *(const float4*)&Wpair[d * 8 + 4];
    WT[0][d] = f2bf(a.x);  WT[1][d] = f2bf(a.y);
    WT[2][d] = f2bf(a.z);  WT[3][d] = f2bf(a.w);
    WT[4][d] = f2bf(b2.x); WT[5][d] = f2bf(b2.y);
    WT[6][d] = f2bf(b2.z); WT[7][d] = f2bf(b2.w);
  }
  __syncthreads();

  // ---- phase 0: scalar + point logits -> L[j][h]
  {
    const float* kbase = proj + ((size_t)b * 512 + j0) * PROJC + 128;
    const float* kpbase = kp + ((size_t)b * 512 + j0) * 96;
    int h = t & 7;
#pragma unroll
    for (int r = 0; r < 2; r++) {
      int j = r * 32 + (t >> 3);
      const float* kr = kbase + (size_t)j * PROJC + h * 16;
      const float* kpr = kpbase + (size_t)j * 96 + h * 12;
      float s = 0.f;
#pragma unroll
      for (int dd = 0; dd < 16; dd++) s += qs[h * 16 + dd] * kr[dd];
      float d2 = 0.f;
#pragma unroll
      for (int p = 0; p < 12; p++) {
        float df = qpi[h * 12 + p] - kpr[p];
        d2 += df * df;
      }
      L[j][h] = s * SCALAR_SCALE - wh[h] * d2 + bp[h];
    }
  }
  __syncthreads();

  // ---- MFMA1
  {
    int w = t >> 6, lane = t & 63;
    int fr = lane & 15, fko = (lane >> 4) * 8;
    f32x4 acc = {0.f, 0.f, 0.f, 0.f};
#pragma unroll
    for (int kk = 0; kk < 128; kk += 32) {
      short8 af = *(const short8*)&WT[fr & 7][kk + fko];
      short8 bf = *(const short8*)&pairN[w * 16 + fr][kk + fko];
      acc = __builtin_amdgcn_mfma_f32_16x16x32_bf16(af, bf, acc, 0, 0, 0);
    }
    int row0 = (lane >> 4) * 4;
    if (row0 < 8) {
      int j = w * 16 + fr;
#pragma unroll
      for (int r = 0; r < 4; r++)
        L[j][row0 + r] += acc[r] * PAIR_SCALE;
    }
  }
  __syncthreads();

  // ---- local max per head
  if (t < 64) {
    int h = t >> 3, seg = t & 7;
    float m = -1e30f;
#pragma unroll
    for (int k = 0; k < 8; k++) m = fmaxf(m, L[seg * 8 + k][h]);
    m = fmaxf(m, __shfl_xor(m, 1));
    m = fmaxf(m, __shfl_xor(m, 2));
    m = fmaxf(m, __shfl_xor(m, 4));
    if (seg == 0) msh[h] = m;
  }
  __syncthreads();

  // ---- P = exp(L - m)
  {
    int j = t & 63, w2 = t >> 6;
    int h0 = w2 * 2, h1 = h0 + 1;
    float p0 = __expf(L[j][h0] - msh[h0]);
    float p1 = __expf(L[j][h1] - msh[h1]);
    Pf[h0][j] = p0; Pf[h1][j] = p1;
    Pb[h0][j] = f2bf(p0); Pb[h1][j] = f2bf(p1);
    float s0 = wred_sum(p0);
    float s1 = wred_sum(p1);
    if (j == 0) { lsh[h0] = s0; lsh[h1] = s1; }
  }
  __syncthreads();

  unsigned short* po = pbuf16 + ((size_t)bi * NSPLIT + c) * PSTRIDE16;
  float* pm = pml + ((size_t)bi * NSPLIT + c) * 16;

  // ---- MFMA3 (out_pair) + out_pg half-sums
  {
    int lane = t & 63, w = t >> 6;
    int colm = lane & 15;
    int kgrp = (lane >> 4) * 8;
#pragma unroll
    for (int mi = 0; mi < 2; mi++) {
      int dt = w * 2 + mi;
      f32x4 acc = {0.f, 0.f, 0.f, 0.f};
#pragma unroll
      for (int kk = 0; kk < 64; kk += 32) {
        short8 af;
#pragma unroll
        for (int q = 0; q < 8; q++)
          af[q] = ((const short*)&pairN[kk + kgrp + q][0])[dt * 16 + colm];
        short8 bf = *(const short8*)&Pb[colm & 7][kk + kgrp];
        acc = __builtin_amdgcn_mfma_f32_16x16x32_bf16(af, bf, acc, 0, 0, 0);
      }
      if (colm < 8) {
        int row0 = (lane >> 4) * 4;
#pragma unroll
        for (int r = 0; r < 4; r++)
          po[colm * 128 + dt * 16 + row0 + r] = f2bf(acc[r]);
      }
    }
  }
  float accg = 0.f;
  int ixg = (t < 96) ? t : t - 96;
  if (t < 192) {
    int jh = (t < 96) ? 0 : 1;
    int hvv = ixg / 12;
    const float* vb = vp + ((size_t)b * 512 + j0 + jh * 32) * 96 + ixg;
#pragma unroll 8
    for (int j = 0; j < 32; j++) accg += Pf[hvv][jh * 32 + j] * vb[(size_t)j * 96];
    if (t < 96) pgpart[ixg] = accg;
  }
  __syncthreads();

  // ---- stage VsN into pairN
  {
    const float* vsb = proj + ((size_t)b * 512 + j0) * PROJC + 256;
#pragma unroll
    for (int it = 0; it < 8; it++) {
      int f = it * 256 + t;
      int j = f >> 5, dq = f & 31;
      float4 v = *(const float4*)&vsb[(size_t)j * PROJC + dq * 4];
      ushort4 o;
      o.x = f2bf(v.x); o.y = f2bf(v.y); o.z = f2bf(v.z); o.w = f2bf(v.w);
      *(ushort4*)&pairN[j][dq * 4] = o;
    }
  }
  if (t >= 96 && t < 192) po[1152 + ixg] = f2bf(pgpart[ixg] + accg);
  if (t < 8) { pm[t] = msh[t]; pm[8 + t] = lsh[t]; }
  __syncthreads();

  // ---- MFMA4: out_s (block diagonal)
  {
    int lane = t & 63, w = t >> 6;
    int colm = lane & 15;
    int kgrp = (lane >> 4) * 8;
#pragma unroll
    for (int mi = 0; mi < 2; mi++) {
      int dt = w * 2 + mi;
      f32x4 acc = {0.f, 0.f, 0.f, 0.f};
#pragma unroll
      for (int kk = 0; kk < 64; kk += 32) {
        short8 af;
#pragma unroll
        for (int q = 0; q < 8; q++)
          af[q] = ((const short*)&pairN[kk + kgrp + q][0])[dt * 16 + colm];
        short8 bf = *(const short8*)&Pb[colm & 7][kk + kgrp];
        acc = __builtin_amdgcn_mfma_f32_16x16x32_bf16(af, bf, acc, 0, 0, 0);
      }
      if (colm == dt) {
        int row0 = (lane >> 4) * 4;
#pragma unroll
        for (int r = 0; r < 4; r++)
          po[1024 + dt * 16 + row0 + r] = f2bf(acc[r]);
      }
    }
  }
}

// ---------------- 6. combine splits (bf16 partials) + frame + norms -> concat
__global__ __launch_bounds__(256) void combine_splits(
    const unsigned short* __restrict__ pbuf16, const float* __restrict__ pml,
    const float* __restrict__ rot, const float* __restrict__ trans,
    float* __restrict__ concat) {
  int bi = blockIdx.x;
  int t = threadIdx.x;
  __shared__ float sc[NSPLIT][8];
  __shared__ float pg[96], plcl[96];
  __shared__ float Rm[9], Tv[3];
  if (t < 9) Rm[t] = rot[bi * 9 + t];
  if (t < 3) Tv[t] = trans[bi * 3 + t];
  const unsigned short* pb = pbuf16 + (size_t)bi * NSPLIT * PSTRIDE16;
  const float* pm = pml + (size_t)bi * NSPLIT * 16;
  if (t < 8) {
    float m[NSPLIT], lv[NSPLIT];
    float M = -1e30f;
#pragma unroll
    for (int cs = 0; cs < NSPLIT; cs++) {
      m[cs] = pm[cs * 16 + t];
      lv[cs] = pm[cs * 16 + 8 + t];
      M = fmaxf(M, m[cs]);
    }
    float D = 0.f, s[NSPLIT];
#pragma unroll
    for (int cs = 0; cs < NSPLIT; cs++) {
      s[cs] = __expf(m[cs] - M);
      D += lv[cs] * s[cs];
    }
    float inv = 1.f / D;
#pragma unroll
    for (int cs = 0; cs < NSPLIT; cs++) sc[cs][t] = s[cs] * inv;
  }
  __syncthreads();
  float* crow = concat + (size_t)bi * CONCATC;
#pragma unroll
  for (int q = 0; q < 4; q++) {
    int idx = q * 256 + t;
    int h = idx >> 7;
    float v = 0.f;
#pragma unroll
    for (int cs = 0; cs < NSPLIT; cs++) v += bf2f(pb[cs * PSTRIDE16 + idx]) * sc[cs][h];
    crow[256 + idx] = v;
  }
  if (t < 128) {
    int h = t >> 4;
    float v = 0.f;
#pragma unroll
    for (int cs = 0; cs < NSPLIT; cs++) v += bf2f(pb[cs * PSTRIDE16 + 1024 + t]) * sc[cs][h];
    crow[t] = v;
  } else if (t < 224) {
    int ix = t - 128, h = ix / 12;
    float v = 0.f;
#pragma unroll
    for (int cs = 0; cs < NSPLIT; cs++) v += bf2f(pb[cs * PSTRIDE16 + 1152 + ix]) * sc[cs][h];
    pg[ix] = v;
  }
  __syncthreads();
  if (t < 96) {
    int hp = t / 3, cc = t % 3;
    float v = 0.f;
#pragma unroll
    for (int r = 0; r < 3; r++) v += Rm[cc * 3 + r] * (pg[hp * 3 + r] - Tv[r]);
    plcl[t] = v;
    crow[128 + t] = v;
  }
  __syncthreads();
  if (t < 32) {
    float v0 = plcl[t * 3], v1 = plcl[t * 3 + 1], v2 = plcl[t * 3 + 2];
    crow[224 + t] = sqrtf(v0 * v0 + v1 * v1 + v2 * v2 + 1e-8f);
  }
}

// ---------------- 7. layernorm (+residual)
__global__ __launch_bounds__(256) void ln_kernel(
    const float* __restrict__ in, const float* __restrict__ res,
    const float* __restrict__ g, const float* __restrict__ bt,
    float* __restrict__ out) {
  int row = blockIdx.x;
  int t = threadIdx.x;
  __shared__ float red[8];
  size_t base = (size_t)row * 512;
  float v0 = in[base + t] + res[base + t];
  float v1 = in[base + t + 256] + res[base + t + 256];
  int wid = t >> 6, lane = t & 63;
  float s = wred_sum(v0 + v1);
  if (lane == 0) red[wid] = s;
  __syncthreads();
  float mean = (red[0] + red[1] + red[2] + red[3]) * (1.f / 512.f);
  float d0 = v0 - mean, d1 = v1 - mean;
  float q = wred_sum(d0 * d0 + d1 * d1);
  __syncthreads();
  if (lane == 0) red[wid] = q;
  __syncthreads();
  float var = (red[0] + red[1] + red[2] + red[3]) * (1.f / 512.f);
  float rs = rsqrtf(var + 1e-3f);
  out[base + t] = d0 * rs * g[t] + bt[t];
  out[base + t + 256] = d1 * rs * g[t + 256] + bt[t + 256];
}

// ---------------------------------------------------------------- launcher
extern "C" void kernel_launch(void* const* d_in, const int* in_sizes, int n_in,
                              void* d_out, int out_size, void* d_ws, size_t ws_size,
                              hipStream_t stream) {
  const float* x      = (const float*)d_in[0];
  const float* pair   = (const float*)d_in[1];
  const float* rot    = (const float*)d_in[2];
  const float* trans  = (const float*)d_in[3];
  const float* Wqs    = (const float*)d_in[4];
  const float* Wks    = (const float*)d_in[5];
  const float* Wvs    = (const float*)d_in[6];
  const float* Wqp    = (const float*)d_in[7];
  const float* Wkp    = (const float*)d_in[8];
  const float* Wvp    = (const float*)d_in[9];
  const float* pw     = (const float*)d_in[10];
  const float* Wpair  = (const float*)d_in[11];
  const float* b_pair = (const float*)d_in[12];
  const float* Wo     = (const float*)d_in[13];
  const float* bo     = (const float*)d_in[14];
  const float* ln1g   = (const float*)d_in[15];
  const float* ln1b   = (const float*)d_in[16];
  const float* ln2g   = (const float*)d_in[17];
  const float* ln2b   = (const float*)d_in[18];
  const float* ffw1   = (const float*)d_in[19];
  const float* ffb1   = (const float*)d_in[20];
  const float* ffw2   = (const float*)d_in[21];
  const float* ffb2   = (const float*)d_in[22];
  const float* ffw3   = (const float*)d_in[23];
  const float* ffb3   = (const float*)d_in[24];
  float* out = (float*)d_out;

  float* ws = (float*)d_ws;
  unsigned short* Wcat_t = (unsigned short*)ws; ws += (704 * 512) / 2;
  unsigned short* Wo_t   = (unsigned short*)ws; ws += (512 * 1280) / 2;
  unsigned short* ff1_t  = (unsigned short*)ws; ws += (512 * 512) / 2;
  unsigned short* ff2_t  = (unsigned short*)ws; ws += (512 * 512) / 2;
  unsigned short* ff3_t  = (unsigned short*)ws; ws += (512 * 512) / 2;
  float* proj   = ws; ws += (size_t)RR * PROJC;
  float* qp     = ws; ws += RR * 96;
  float* kp     = ws; ws += RR * 96;
  float* vp     = ws; ws += RR * 96;
  unsigned short* pbuf16 = (unsigned short*)ws; ws += ((size_t)RR * NSPLIT * PSTRIDE16) / 2;
  float* pml    = ws; ws += (size_t)RR * NSPLIT * 16;
  float* concat = ws; ws += (size_t)RR * CONCATC;
  float* tmp1   = ws; ws += RR * 512;
  float* a      = ws; ws += RR * 512;
  float* h1     = ws; ws += RR * 512;
  float* h2     = ws; ws += RR * 512;
  float* f      = ws; ws += RR * 512;

  dim3 b256(256);
  hipLaunchKernelGGL(prep_weights, dim3(16, 40, 5), b256, 0, stream,
                     Wo, ffw1, ffw2, ffw3, Wo_t, ff1_t, ff2_t, ff3_t,
                     Wqs, Wks, Wvs, Wqp, Wkp, Wvp, Wcat_t);
  hipLaunchKernelGGL(gemm_bf16_32, dim3(11, 32), b256, 0, stream,
                     x, 512, Wcat_t, 512, proj, PROJC, (const float*)nullptr, 0);
  hipLaunchKernelGGL(pointxform, dim3(RR), dim3(128), 0, stream,
                     proj, rot, trans, qp, kp, vp);
  hipLaunchKernelGGL(flash_split, dim3(RR, NSPLIT), b256, 0, stream,
                     pair, Wpair, proj, qp, kp, vp, pw, b_pair, pbuf16, pml);
  hipLaunchKernelGGL(combine_splits, dim3(RR), b256, 0, stream,
                     pbuf16, pml, rot, trans, concat);
  hipLaunchKernelGGL(gemm_bf16_32, dim3(8, 32), b256, 0, stream,
                     concat, CONCATC, Wo_t, 1280, tmp1, 512, bo, 0);
  hipLaunchKernelGGL(ln_kernel, dim3(RR), b256, 0, stream, tmp1, x, ln1g, ln1b, a);
  hipLaunchKernelGGL(gemm_bf16_32, dim3(8, 32), b256, 0, stream,
                     a, 512, ff1_t, 512, h1, 512, ffb1, 1);
  hipLaunchKernelGGL(gemm_bf16_32, dim3(8, 32), b256, 0, stream,
                     h1, 512, ff2_t, 512, h2, 512, ffb2, 1);
  hipLaunchKernelGGL(gemm_bf16_32, dim3(8, 32), b256, 0, stream,
                     h2, 512, ff3_t, 512, f, 512, ffb3, 0);
  hipLaunchKernelGGL(ln_kernel, dim3(RR), b256, 0, stream, f, a, ln2g, ln2b, out);
}

// Round 17
// 169.264 us; speedup vs baseline: 1.0446x; 1.0042x over previous
//
#include <hip/hip_runtime.h>
#include <math.h>

#define Bb 2
#define Nn 512
#define RR 1024
#define HH 8
#define PROJC 704
#define CONCATC 1280
#define PSTRIDE16 1280
#define NSPLIT 8
#define CH 64

#define SCALAR_SCALE 0.14433756729740643f
#define POINT_SCALE  0.13608276348795434f
#define PAIR_SCALE   0.5773502691896258f

typedef __attribute__((ext_vector_type(4))) float f32x4;
typedef __attribute__((ext_vector_type(8))) short short8;
typedef __attribute__((ext_vector_type(8))) unsigned short ush8;

__device__ __forceinline__ float wred_sum(float v) {
#pragma unroll
  for (int o = 1; o < 64; o <<= 1) v += __shfl_xor(v, o);
  return v;
}
__device__ __forceinline__ unsigned short f2bf(float f) {
  unsigned int u = __float_as_uint(f);
  unsigned int r = (u + 0x7FFFu + ((u >> 16) & 1u)) >> 16;
  return (unsigned short)r;
}
__device__ __forceinline__ float bf2f(unsigned short u) {
  return __uint_as_float(((unsigned int)u) << 16);
}
// swizzled ushort index into a [64][136] tile: XOR byte-offset with ((row>>3)&3)<<4
__device__ __forceinline__ int swzi(int row, int colByte) {
  return row * 136 + (((colByte) ^ (((row >> 3) & 3) << 4)) >> 1);
}

// ---------------- 1. prep: z<4 -> transpose+cvt weights; z==4 -> gather Wcat_t
__global__ __launch_bounds__(256) void prep_weights(
    const float* __restrict__ w0, const float* __restrict__ w1,
    const float* __restrict__ w2, const float* __restrict__ w3,
    unsigned short* __restrict__ o0, unsigned short* __restrict__ o1,
    unsigned short* __restrict__ o2, unsigned short* __restrict__ o3,
    const float* __restrict__ Wqs, const float* __restrict__ Wks,
    const float* __restrict__ Wvs, const float* __restrict__ Wqp,
    const float* __restrict__ Wkp, const float* __restrict__ Wvp,
    unsigned short* __restrict__ Wt) {
  int z = blockIdx.z;
  int t = threadIdx.x;
  if (z < 4) {
    const float* in = (z == 0) ? w0 : (z == 1) ? w1 : (z == 2) ? w2 : w3;
    unsigned short* out = (z == 0) ? o0 : (z == 1) ? o1 : (z == 2) ? o2 : o3;
    int K = (z == 0) ? 1280 : 512;
    int k0 = blockIdx.y * 32, n0 = blockIdx.x * 32;
    if (k0 >= K) return;
    __shared__ float tile[32][33];
    int r = t >> 3, cq = (t & 7) * 4;
    float4 v = *(const float4*)&in[(size_t)(k0 + r) * 512 + n0 + cq];
    tile[r][cq] = v.x; tile[r][cq + 1] = v.y; tile[r][cq + 2] = v.z; tile[r][cq + 3] = v.w;
    __syncthreads();
    ushort4 o4;
    o4.x = f2bf(tile[cq + 0][r]);
    o4.y = f2bf(tile[cq + 1][r]);
    o4.z = f2bf(tile[cq + 2][r]);
    o4.w = f2bf(tile[cq + 3][r]);
    *(ushort4*)&out[(size_t)(n0 + r) * K + k0 + cq] = o4;
  } else {
    for (int c = blockIdx.y * 16 + blockIdx.x; c < 704; c += 640) {
      for (int k = t; k < 512; k += 256) {
        float val = 0.f;
        if (c < 128)      val = Wqs[k * 128 + c];
        else if (c < 256) val = Wks[k * 128 + c - 128];
        else if (c < 384) val = Wvs[k * 128 + c - 256];
        else if (c < 480) val = Wqp[k * 96 + c - 384];
        else if (c < 576) val = Wkp[k * 96 + c - 480];
        else if (c < 672) val = Wvp[k * 96 + c - 576];
        Wt[(size_t)c * 512 + k] = f2bf(val);
      }
    }
  }
}

// ---------------- 3. bf16 MFMA GEMM, 32x64 tile
__global__ __launch_bounds__(256) void gemm_bf16_32(
    const float* __restrict__ A, int lda,
    const unsigned short* __restrict__ Bt, int K,
    float* __restrict__ C, int ldc,
    const float* __restrict__ bias, int relu) {
  __shared__ unsigned short As[32][72];
  __shared__ unsigned short Bs[64][72];
  int t = threadIdx.x;
  int lane = t & 63, w = t >> 6;
  int wc = w * 16;
  int fr = lane & 15, fk = (lane >> 4) * 8;
  f32x4 zero = {0.f, 0.f, 0.f, 0.f};
  f32x4 acc0 = zero, acc1 = zero;
  int bm = blockIdx.y * 32, bn = blockIdx.x * 64;
  int ar = t >> 3, ac = (t & 7) * 8;
  int br = t >> 2, bc = (t & 3) * 16;
  const float* Arow = A + (size_t)(bm + ar) * lda + ac;
  const unsigned short* Brow = Bt + (size_t)(bn + br) * K + bc;
  for (int k0 = 0; k0 < K; k0 += 64) {
    float4 a0 = *(const float4*)(Arow + k0);
    float4 a1 = *(const float4*)(Arow + k0 + 4);
    ush8 ap;
    ap[0] = f2bf(a0.x); ap[1] = f2bf(a0.y); ap[2] = f2bf(a0.z); ap[3] = f2bf(a0.w);
    ap[4] = f2bf(a1.x); ap[5] = f2bf(a1.y); ap[6] = f2bf(a1.z); ap[7] = f2bf(a1.w);
    ush8 b0 = *(const ush8*)(Brow + k0);
    ush8 b1 = *(const ush8*)(Brow + k0 + 8);
    *(ush8*)&As[ar][ac] = ap;
    *(ush8*)&Bs[br][bc] = b0;
    *(ush8*)&Bs[br][bc + 8] = b1;
    __syncthreads();
#pragma unroll
    for (int kk = 0; kk < 64; kk += 32) {
      short8 af0 = *(const short8*)&As[fr][kk + fk];
      short8 af1 = *(const short8*)&As[16 + fr][kk + fk];
      short8 bf = *(const short8*)&Bs[wc + fr][kk + fk];
      acc0 = __builtin_amdgcn_mfma_f32_16x16x32_bf16(af0, bf, acc0, 0, 0, 0);
      acc1 = __builtin_amdgcn_mfma_f32_16x16x32_bf16(af1, bf, acc1, 0, 0, 0);
    }
    __syncthreads();
  }
  int col = bn + wc + fr;
  float bv = bias ? bias[col] : 0.f;
#pragma unroll
  for (int mi = 0; mi < 2; mi++) {
    f32x4 av = (mi == 0) ? acc0 : acc1;
#pragma unroll
    for (int r = 0; r < 4; r++) {
      int row = bm + mi * 16 + (lane >> 4) * 4 + r;
      float v2 = av[r] + bv;
      if (relu) v2 = fmaxf(v2, 0.f);
      C[(size_t)row * ldc + col] = v2;
    }
  }
}

// ---------------- 4. rotate/translate points to global
__global__ __launch_bounds__(128) void pointxform(
    const float* __restrict__ proj, const float* __restrict__ rot,
    const float* __restrict__ trans, float* __restrict__ qp,
    float* __restrict__ kp, float* __restrict__ vp) {
  int bn = blockIdx.x;
  int t = threadIdx.x;
  __shared__ float R[9];
  __shared__ float T[3];
  if (t < 9) R[t] = rot[bn * 9 + t];
  if (t < 3) T[t] = trans[bn * 3 + t];
  __syncthreads();
  if (t < 96) {
    int which = t >> 5;
    int pt = t & 31;
    const float* src = proj + (size_t)bn * PROJC + 384 + which * 96 + pt * 3;
    float c0 = src[0], c1 = src[1], c2 = src[2];
    float* dst = (which == 0 ? qp : (which == 1 ? kp : vp)) + (size_t)bn * 96 + pt * 3;
#pragma unroll
    for (int r = 0; r < 3; r++)
      dst[r] = c0 * R[0 * 3 + r] + c1 * R[1 * 3 + r] + c2 * R[2 * 3 + r] + T[r];
  }
}

// ---------------- 5. split-j fused pass (R16 + XOR-swizzled pairN)
__global__ __launch_bounds__(256) void flash_split(
    const float* __restrict__ pair, const float* __restrict__ Wpair,
    const float* __restrict__ proj, const float* __restrict__ qp,
    const float* __restrict__ kp, const float* __restrict__ vp,
    const float* __restrict__ pw, const float* __restrict__ b_pair,
    unsigned short* __restrict__ pbuf16, float* __restrict__ pml) {
  int bi = blockIdx.x, c = blockIdx.y;
  int b = bi >> 9;
  int j0 = c * CH;
  int t = threadIdx.x;
  __shared__ unsigned short pairN[64 * 136];  // swizzled bf16 tile
  __shared__ unsigned short WT[8][136];
  __shared__ unsigned short Pb[8][72];
  __shared__ float L[64][9];
  __shared__ float Pf[8][68];
  __shared__ float qs[128], qpi[96], wh[8], bp[8];
  __shared__ float msh[8], lsh[8];
  __shared__ float pgpart[96];

  const float* pbase = pair + ((size_t)bi * 512 + j0) * 128;

  // ---- stage pairN (swizzled writes) + qs/qpi/wh/bp + WT
#pragma unroll
  for (int it = 0; it < 8; it++) {
    int f = it * 256 + t;
    int j = f >> 5, dq = f & 31;
    float4 v = *(const float4*)&pbase[(size_t)j * 128 + dq * 4];
    ushort4 o;
    o.x = f2bf(v.x); o.y = f2bf(v.y); o.z = f2bf(v.z); o.w = f2bf(v.w);
    *(ushort4*)&pairN[swzi(j, dq * 8)] = o;
  }
  if (t < 32) *(float4*)&qs[t * 4] = *(const float4*)&proj[(size_t)bi * PROJC + t * 4];
  if (t >= 32 && t < 56) *(float4*)&qpi[(t - 32) * 4] = *(const float4*)&qp[(size_t)bi * 96 + (t - 32) * 4];
  if (t >= 56 && t < 64) {
    wh[t - 56] = 0.5f * log1pf(__expf(pw[t - 56])) * POINT_SCALE;
    bp[t - 56] = b_pair[t - 56] * PAIR_SCALE;
  }
  if (t >= 64 && t < 192) {
    int d = t - 64;
    float4 a = *(const float4*)&Wpair[d * 8];
    float4 b2 = *(const float4*)&Wpair[d * 8 + 4];
    WT[0][d] = f2bf(a.x);  WT[1][d] = f2bf(a.y);
    WT[2][d] = f2bf(a.z);  WT[3][d] = f2bf(a.w);
    WT[4][d] = f2bf(b2.x); WT[5][d] = f2bf(b2.y);
    WT[6][d] = f2bf(b2.z); WT[7][d] = f2bf(b2.w);
  }
  __syncthreads();

  // ---- phase 0: scalar + point logits -> L[j][h]
  {
    const float* kbase = proj + ((size_t)b * 512 + j0) * PROJC + 128;
    const float* kpbase = kp + ((size_t)b * 512 + j0) * 96;
    int h = t & 7;
#pragma unroll
    for (int r = 0; r < 2; r++) {
      int j = r * 32 + (t >> 3);
      const float* kr = kbase + (size_t)j * PROJC + h * 16;
      const float* kpr = kpbase + (size_t)j * 96 + h * 12;
      float s = 0.f;
#pragma unroll
      for (int dd = 0; dd < 16; dd++) s += qs[h * 16 + dd] * kr[dd];
      float d2 = 0.f;
#pragma unroll
      for (int p = 0; p < 12; p++) {
        float df = qpi[h * 12 + p] - kpr[p];
        d2 += df * df;
      }
      L[j][h] = s * SCALAR_SCALE - wh[h] * d2 + bp[h];
    }
  }
  __syncthreads();

  // ---- MFMA1: L[j][h] += PAIR_SCALE * (W^T x pair^T)[h][j]
  {
    int w = t >> 6, lane = t & 63;
    int fr = lane & 15, fko = (lane >> 4) * 8;
    int row = w * 16 + fr;
    f32x4 acc = {0.f, 0.f, 0.f, 0.f};
#pragma unroll
    for (int kk = 0; kk < 128; kk += 32) {
      short8 af = *(const short8*)&WT[fr & 7][kk + fko];
      short8 bf = *(const short8*)&pairN[swzi(row, (kk + fko) * 2)];
      acc = __builtin_amdgcn_mfma_f32_16x16x32_bf16(af, bf, acc, 0, 0, 0);
    }
    int row0 = (lane >> 4) * 4;
    if (row0 < 8) {
      int j = row;
#pragma unroll
      for (int r = 0; r < 4; r++)
        L[j][row0 + r] += acc[r] * PAIR_SCALE;
    }
  }
  __syncthreads();

  // ---- local max per head
  if (t < 64) {
    int h = t >> 3, seg = t & 7;
    float m = -1e30f;
#pragma unroll
    for (int k = 0; k < 8; k++) m = fmaxf(m, L[seg * 8 + k][h]);
    m = fmaxf(m, __shfl_xor(m, 1));
    m = fmaxf(m, __shfl_xor(m, 2));
    m = fmaxf(m, __shfl_xor(m, 4));
    if (seg == 0) msh[h] = m;
  }
  __syncthreads();

  // ---- P = exp(L - m)
  {
    int j = t & 63, w2 = t >> 6;
    int h0 = w2 * 2, h1 = h0 + 1;
    float p0 = __expf(L[j][h0] - msh[h0]);
    float p1 = __expf(L[j][h1] - msh[h1]);
    Pf[h0][j] = p0; Pf[h1][j] = p1;
    Pb[h0][j] = f2bf(p0); Pb[h1][j] = f2bf(p1);
    float s0 = wred_sum(p0);
    float s1 = wred_sum(p1);
    if (j == 0) { lsh[h0] = s0; lsh[h1] = s1; }
  }
  __syncthreads();

  unsigned short* po = pbuf16 + ((size_t)bi * NSPLIT + c) * PSTRIDE16;
  float* pm = pml + ((size_t)bi * NSPLIT + c) * 16;

  // ---- MFMA3 (out_pair) + out_pg half-sums
  {
    int lane = t & 63, w = t >> 6;
    int colm = lane & 15;
    int kgrp = (lane >> 4) * 8;
#pragma unroll
    for (int mi = 0; mi < 2; mi++) {
      int dt = w * 2 + mi;
      f32x4 acc = {0.f, 0.f, 0.f, 0.f};
#pragma unroll
      for (int kk = 0; kk < 64; kk += 32) {
        short8 af;
#pragma unroll
        for (int q = 0; q < 8; q++)
          af[q] = (short)pairN[swzi(kk + kgrp + q, (dt * 16 + colm) * 2)];
        short8 bf = *(const short8*)&Pb[colm & 7][kk + kgrp];
        acc = __builtin_amdgcn_mfma_f32_16x16x32_bf16(af, bf, acc, 0, 0, 0);
      }
      if (colm < 8) {
        int row0 = (lane >> 4) * 4;
#pragma unroll
        for (int r = 0; r < 4; r++)
          po[colm * 128 + dt * 16 + row0 + r] = f2bf(acc[r]);
      }
    }
  }
  float accg = 0.f;
  int ixg = (t < 96) ? t : t - 96;
  if (t < 192) {
    int jh = (t < 96) ? 0 : 1;
    int hvv = ixg / 12;
    const float* vb = vp + ((size_t)b * 512 + j0 + jh * 32) * 96 + ixg;
#pragma unroll 8
    for (int j = 0; j < 32; j++) accg += Pf[hvv][jh * 32 + j] * vb[(size_t)j * 96];
    if (t < 96) pgpart[ixg] = accg;
  }
  __syncthreads();

  // ---- stage VsN into pairN (swizzled)
  {
    const float* vsb = proj + ((size_t)b * 512 + j0) * PROJC + 256;
#pragma unroll
    for (int it = 0; it < 8; it++) {
      int f = it * 256 + t;
      int j = f >> 5, dq = f & 31;
      float4 v = *(const float4*)&vsb[(size_t)j * PROJC + dq * 4];
      ushort4 o;
      o.x = f2bf(v.x); o.y = f2bf(v.y); o.z = f2bf(v.z); o.w = f2bf(v.w);
      *(ushort4*)&pairN[swzi(j, dq * 8)] = o;
    }
  }
  if (t >= 96 && t < 192) po[1152 + ixg] = f2bf(pgpart[ixg] + accg);
  if (t < 8) { pm[t] = msh[t]; pm[8 + t] = lsh[t]; }
  __syncthreads();

  // ---- MFMA4: out_s (block diagonal)
  {
    int lane = t & 63, w = t >> 6;
    int colm = lane & 15;
    int kgrp = (lane >> 4) * 8;
#pragma unroll
    for (int mi = 0; mi < 2; mi++) {
      int dt = w * 2 + mi;
      f32x4 acc = {0.f, 0.f, 0.f, 0.f};
#pragma unroll
      for (int kk = 0; kk < 64; kk += 32) {
        short8 af;
#pragma unroll
        for (int q = 0; q < 8; q++)
          af[q] = (short)pairN[swzi(kk + kgrp + q, (dt * 16 + colm) * 2)];
        short8 bf = *(const short8*)&Pb[colm & 7][kk + kgrp];
        acc = __builtin_amdgcn_mfma_f32_16x16x32_bf16(af, bf, acc, 0, 0, 0);
      }
      if (colm == dt) {
        int row0 = (lane >> 4) * 4;
#pragma unroll
        for (int r = 0; r < 4; r++)
          po[1024 + dt * 16 + row0 + r] = f2bf(acc[r]);
      }
    }
  }
}

// ---------------- 6. combine splits (bf16 partials) + frame + norms -> concat
__global__ __launch_bounds__(256) void combine_splits(
    const unsigned short* __restrict__ pbuf16, const float* __restrict__ pml,
    const float* __restrict__ rot, const float* __restrict__ trans,
    float* __restrict__ concat) {
  int bi = blockIdx.x;
  int t = threadIdx.x;
  __shared__ float sc[NSPLIT][8];
  __shared__ float pg[96], plcl[96];
  __shared__ float Rm[9], Tv[3];
  if (t < 9) Rm[t] = rot[bi * 9 + t];
  if (t < 3) Tv[t] = trans[bi * 3 + t];
  const unsigned short* pb = pbuf16 + (size_t)bi * NSPLIT * PSTRIDE16;
  const float* pm = pml + (size_t)bi * NSPLIT * 16;
  if (t < 8) {
    float m[NSPLIT], lv[NSPLIT];
    float M = -1e30f;
#pragma unroll
    for (int cs = 0; cs < NSPLIT; cs++) {
      m[cs] = pm[cs * 16 + t];
      lv[cs] = pm[cs * 16 + 8 + t];
      M = fmaxf(M, m[cs]);
    }
    float D = 0.f, s[NSPLIT];
#pragma unroll
    for (int cs = 0; cs < NSPLIT; cs++) {
      s[cs] = __expf(m[cs] - M);
      D += lv[cs] * s[cs];
    }
    float inv = 1.f / D;
#pragma unroll
    for (int cs = 0; cs < NSPLIT; cs++) sc[cs][t] = s[cs] * inv;
  }
  __syncthreads();
  float* crow = concat + (size_t)bi * CONCATC;
#pragma unroll
  for (int q = 0; q < 4; q++) {
    int idx = q * 256 + t;
    int h = idx >> 7;
    float v = 0.f;
#pragma unroll
    for (int cs = 0; cs < NSPLIT; cs++) v += bf2f(pb[cs * PSTRIDE16 + idx]) * sc[cs][h];
    crow[256 + idx] = v;
  }
  if (t < 128) {
    int h = t >> 4;
    float v = 0.f;
#pragma unroll
    for (int cs = 0; cs < NSPLIT; cs++) v += bf2f(pb[cs * PSTRIDE16 + 1024 + t]) * sc[cs][h];
    crow[t] = v;
  } else if (t < 224) {
    int ix = t - 128, h = ix / 12;
    float v = 0.f;
#pragma unroll
    for (int cs = 0; cs < NSPLIT; cs++) v += bf2f(pb[cs * PSTRIDE16 + 1152 + ix]) * sc[cs][h];
    pg[ix] = v;
  }
  __syncthreads();
  if (t < 96) {
    int hp = t / 3, cc = t % 3;
    float v = 0.f;
#pragma unroll
    for (int r = 0; r < 3; r++) v += Rm[cc * 3 + r] * (pg[hp * 3 + r] - Tv[r]);
    plcl[t] = v;
    crow[128 + t] = v;
  }
  __syncthreads();
  if (t < 32) {
    float v0 = plcl[t * 3], v1 = plcl[t * 3 + 1], v2 = plcl[t * 3 + 2];
    crow[224 + t] = sqrtf(v0 * v0 + v1 * v1 + v2 * v2 + 1e-8f);
  }
}

// ---------------- 7. layernorm (+residual)
__global__ __launch_bounds__(256) void ln_kernel(
    const float* __restrict__ in, const float* __restrict__ res,
    const float* __restrict__ g, const float* __restrict__ bt,
    float* __restrict__ out) {
  int row = blockIdx.x;
  int t = threadIdx.x;
  __shared__ float red[8];
  size_t base = (size_t)row * 512;
  float v0 = in[base + t] + res[base + t];
  float v1 = in[base + t + 256] + res[base + t + 256];
  int wid = t >> 6, lane = t & 63;
  float s = wred_sum(v0 + v1);
  if (lane == 0) red[wid] = s;
  __syncthreads();
  float mean = (red[0] + red[1] + red[2] + red[3]) * (1.f / 512.f);
  float d0 = v0 - mean, d1 = v1 - mean;
  float q = wred_sum(d0 * d0 + d1 * d1);
  __syncthreads();
  if (lane == 0) red[wid] = q;
  __syncthreads();
  float var = (red[0] + red[1] + red[2] + red[3]) * (1.f / 512.f);
  float rs = rsqrtf(var + 1e-3f);
  out[base + t] = d0 * rs * g[t] + bt[t];
  out[base + t + 256] = d1 * rs * g[t + 256] + bt[t + 256];
}

// ---------------------------------------------------------------- launcher
extern "C" void kernel_launch(void* const* d_in, const int* in_sizes, int n_in,
                              void* d_out, int out_size, void* d_ws, size_t ws_size,
                              hipStream_t stream) {
  const float* x      = (const float*)d_in[0];
  const float* pair   = (const float*)d_in[1];
  const float* rot    = (const float*)d_in[2];
  const float* trans  = (const float*)d_in[3];
  const float* Wqs    = (const float*)d_in[4];
  const float* Wks    = (const float*)d_in[5];
  const float* Wvs    = (const float*)d_in[6];
  const float* Wqp    = (const float*)d_in[7];
  const float* Wkp    = (const float*)d_in[8];
  const float* Wvp    = (const float*)d_in[9];
  const float* pw     = (const float*)d_in[10];
  const float* Wpair  = (const float*)d_in[11];
  const float* b_pair = (const float*)d_in[12];
  const float* Wo     = (const float*)d_in[13];
  const float* bo     = (const float*)d_in[14];
  const float* ln1g   = (const float*)d_in[15];
  const float* ln1b   = (const float*)d_in[16];
  const float* ln2g   = (const float*)d_in[17];
  const float* ln2b   = (const float*)d_in[18];
  const float* ffw1   = (const float*)d_in[19];
  const float* ffb1   = (const float*)d_in[20];
  const float* ffw2   = (const float*)d_in[21];
  const float* ffb2   = (const float*)d_in[22];
  const float* ffw3   = (const float*)d_in[23];
  const float* ffb3   = (const float*)d_in[24];
  float* out = (float*)d_out;

  float* ws = (float*)d_ws;
  unsigned short* Wcat_t = (unsigned short*)ws; ws += (704 * 512) / 2;
  unsigned short* Wo_t   = (unsigned short*)ws; ws += (512 * 1280) / 2;
  unsigned short* ff1_t  = (unsigned short*)ws; ws += (512 * 512) / 2;
  unsigned short* ff2_t  = (unsigned short*)ws; ws += (512 * 512) / 2;
  unsigned short* ff3_t  = (unsigned short*)ws; ws += (512 * 512) / 2;
  float* proj   = ws; ws += (size_t)RR * PROJC;
  float* qp     = ws; ws += RR * 96;
  float* kp     = ws; ws += RR * 96;
  float* vp     = ws; ws += RR * 96;
  unsigned short* pbuf16 = (unsigned short*)ws; ws += ((size_t)RR * NSPLIT * PSTRIDE16) / 2;
  float* pml    = ws; ws += (size_t)RR * NSPLIT * 16;
  float* concat = ws; ws += (size_t)RR * CONCATC;
  float* tmp1   = ws; ws += RR * 512;
  float* a      = ws; ws += RR * 512;
  float* h1     = ws; ws += RR * 512;
  float* h2     = ws; ws += RR * 512;
  float* f      = ws; ws += RR * 512;

  dim3 b256(256);
  hipLaunchKernelGGL(prep_weights, dim3(16, 40, 5), b256, 0, stream,
                     Wo, ffw1, ffw2, ffw3, Wo_t, ff1_t, ff2_t, ff3_t,
                     Wqs, Wks, Wvs, Wqp, Wkp, Wvp, Wcat_t);
  hipLaunchKernelGGL(gemm_bf16_32, dim3(11, 32), b256, 0, stream,
                     x, 512, Wcat_t, 512, proj, PROJC, (const float*)nullptr, 0);
  hipLaunchKernelGGL(pointxform, dim3(RR), dim3(128), 0, stream,
                     proj, rot, trans, qp, kp, vp);
  hipLaunchKernelGGL(flash_split, dim3(RR, NSPLIT), b256, 0, stream,
                     pair, Wpair, proj, qp, kp, vp, pw, b_pair, pbuf16, pml);
  hipLaunchKernelGGL(combine_splits, dim3(RR), b256, 0, stream,
                     pbuf16, pml, rot, trans, concat);
  hipLaunchKernelGGL(gemm_bf16_32, dim3(8, 32), b256, 0, stream,
                     concat, CONCATC, Wo_t, 1280, tmp1, 512, bo, 0);
  hipLaunchKernelGGL(ln_kernel, dim3(RR), b256, 0, stream, tmp1, x, ln1g, ln1b, a);
  hipLaunchKernelGGL(gemm_bf16_32, dim3(8, 32), b256, 0, stream,
                     a, 512, ff1_t, 512, h1, 512, ffb1, 1);
  hipLaunchKernelGGL(gemm_bf16_32, dim3(8, 32), b256, 0, stream,
                     h1, 512, ff2_t, 512, h2, 512, ffb2, 1);
  hipLaunchKernelGGL(gemm_bf16_32, dim3(8, 32), b256, 0, stream,
                     h2, 512, ff3_t, 512, f, 512, ffb3, 0);
  hipLaunchKernelGGL(ln_kernel, dim3(RR), b256, 0, stream, f, a, ln2g, ln2b, out);
}